// Round 6
// baseline (517.674 us; speedup 1.0000x reference)
//
#include <hip/hip_runtime.h>

#define BN 4
#define CC 256
#define NN 4096
#define CR 32
#define OCH 128
#define SEGS 8

typedef float f32x4 __attribute__((ext_vector_type(4)));
typedef short short8 __attribute__((ext_vector_type(8)));
typedef unsigned short u16x8 __attribute__((ext_vector_type(8)));
typedef unsigned short u16x4 __attribute__((ext_vector_type(4)));

__device__ __forceinline__ unsigned short f2b(float f) {
  unsigned u = __builtin_bit_cast(unsigned, f);
  u += 0x7fff + ((u >> 16) & 1);
  return (unsigned short)(u >> 16);
}
__device__ __forceinline__ float b2f(unsigned short h) {
  unsigned u = ((unsigned)h) << 16;
  return __builtin_bit_cast(float, u);
}

// ---------------------------------------------------------------------------
// cast wq / wv to bf16
__global__ __launch_bounds__(256) void k_wcast(const float* __restrict__ wq,
    const float* __restrict__ wv, unsigned short* __restrict__ wqb,
    unsigned short* __restrict__ wvb) {
  const int gid = (blockIdx.x * 256 + threadIdx.x) * 4;
  const float* src = blockIdx.y ? wv : wq;
  unsigned short* dst = blockIdx.y ? wvb : wqb;
  const float4 v = *(const float4*)(src + gid);
  u16x4 o; o[0] = f2b(v.x); o[1] = f2b(v.y); o[2] = f2b(v.z); o[3] = f2b(v.w);
  *(u16x4*)(dst + gid) = o;
}

// ---------------------------------------------------------------------------
// transpose+cast: x[b][c][n] f32 -> xt[b][n][c] bf16
__global__ __launch_bounds__(256) void k_xt(const float* __restrict__ x,
    unsigned short* __restrict__ xt) {
  __shared__ unsigned short T[64][65];
  const int b = blockIdx.z, c0 = blockIdx.y * 64, n0 = blockIdx.x * 64;
  const int t = threadIdx.x;
  for (int idx = t; idx < 4096; idx += 256) {
    int i = idx >> 6, j = idx & 63;
    T[i][j] = f2b(x[((size_t)(b * CC + c0 + i)) * NN + n0 + j]);
  }
  __syncthreads();
  for (int idx = t; idx < 4096; idx += 256) {
    int j = idx >> 6, i = idx & 63;
    xt[((size_t)(b * NN + n0 + j)) * CC + c0 + i] = T[i][j];
  }
}

// ---------------------------------------------------------------------------
// MFMA projection GEMM: out[b][c][n] = bias[c] + sum_j W[c][j] xt[b][n][j]
__global__ __launch_bounds__(256) void k_projm(const unsigned short* __restrict__ xt,
    const unsigned short* __restrict__ wqb, const float* __restrict__ bq,
    const unsigned short* __restrict__ wvb, const float* __restrict__ bv,
    unsigned short* __restrict__ q1b, unsigned short* __restrict__ Vb) {
  const int b = blockIdx.y, n0 = blockIdx.x * 32, which = blockIdx.z;
  const unsigned short* W = which ? wvb : wqb;
  const float* bias = which ? bv : bq;
  unsigned short* out = which ? Vb : q1b;
  const int t = threadIdx.x;
  const int w = t >> 6, l = t & 63;
  const int lo = l & 15, hi = l >> 4;
  const int oc0 = w * 64;
  f32x4 acc[4][2];
#pragma unroll
  for (int ct = 0; ct < 4; ++ct)
#pragma unroll
    for (int nt = 0; nt < 2; ++nt) acc[ct][nt] = (f32x4){0.f, 0.f, 0.f, 0.f};
  const unsigned short* wb = W + (size_t)(oc0 + lo) * CC + hi * 8;
  const unsigned short* xb = xt + ((size_t)(b * NN + n0 + lo)) * CC + hi * 8;
#pragma unroll
  for (int k0 = 0; k0 < CC; k0 += 32) {
    short8 aw[4], bx[2];
#pragma unroll
    for (int ct = 0; ct < 4; ++ct) aw[ct] = *(const short8*)(wb + ct * 16 * CC + k0);
#pragma unroll
    for (int nt = 0; nt < 2; ++nt) bx[nt] = *(const short8*)(xb + nt * 16 * CC + k0);
#pragma unroll
    for (int ct = 0; ct < 4; ++ct)
#pragma unroll
      for (int nt = 0; nt < 2; ++nt)
        acc[ct][nt] = __builtin_amdgcn_mfma_f32_16x16x32_bf16(aw[ct], bx[nt], acc[ct][nt], 0, 0, 0);
  }
#pragma unroll
  for (int ct = 0; ct < 4; ++ct) {
#pragma unroll
    for (int r = 0; r < 4; ++r) {
      const int c = oc0 + ct * 16 + hi * 4 + r;
      const float bvv = bias[c];
#pragma unroll
      for (int nt = 0; nt < 2; ++nt)
        out[((size_t)(b * CC + c)) * NN + n0 + nt * 16 + lo] = f2b(acc[ct][nt][r] + bvv);
    }
  }
}

// ---------------------------------------------------------------------------
// grouped conv1d (bf16 in, f32 out)
__global__ __launch_bounds__(256) void k_adj1(const unsigned short* __restrict__ q1,
    const float* __restrict__ w1, const float* __restrict__ b1,
    float* __restrict__ q2) {
  const int gid = blockIdx.x * 256 + threadIdx.x;  // B*32*N
  const int n = gid & (NN - 1);
  const int o = (gid >> 12) & 31;
  const int b = gid >> 17;
  const unsigned short* base = q1 + ((size_t)b * CC + o * 8) * NN;
  float s = b1[o];
#pragma unroll
  for (int i = 0; i < 8; ++i) {
    const unsigned short* r = base + (size_t)i * NN;
    const float wa = w1[o * 24 + i * 3 + 0];
    const float wb = w1[o * 24 + i * 3 + 1];
    const float wc = w1[o * 24 + i * 3 + 2];
    if (n > 0) s += wa * b2f(r[n - 1]);
    s += wb * b2f(r[n]);
    if (n < NN - 1) s += wc * b2f(r[n + 1]);
  }
  q2[((size_t)b * CR + o) * NN + n] = s;
}

// ---------------------------------------------------------------------------
// conv1d 32->64ch, writes bf16 TRANSPOSED Qt[b][n][32], Kt[b][n][32]
__global__ __launch_bounds__(256) void k_adj2(const float* __restrict__ q2,
    const float* __restrict__ w2, const float* __restrict__ b2,
    unsigned short* __restrict__ Qt, unsigned short* __restrict__ Kt) {
  __shared__ float q2s[32][66];
  __shared__ float w2t[96][64];
  __shared__ float b2s[64];
  const int b = blockIdx.y, n0 = blockIdx.x * 64;
  const int t = threadIdx.x;
  for (int idx = t; idx < 32 * 66; idx += 256) {
    int c = idx / 66, nn = idx % 66;
    int n = n0 + nn - 1;
    q2s[c][nn] = (n >= 0 && n < NN) ? q2[((size_t)b * CR + c) * NN + n] : 0.f;
  }
  for (int idx = t; idx < 96 * 64; idx += 256) {
    int k = idx & 63, ct = idx >> 6;
    w2t[ct][k] = w2[k * 96 + ct];
  }
  if (t < 64) b2s[t] = b2[t];
  __syncthreads();
  const int nn = t & 63, kh = t >> 6;
  float acc[16];
#pragma unroll
  for (int i = 0; i < 16; ++i) acc[i] = b2s[kh * 16 + i];
  for (int c = 0; c < 32; ++c) {
    const float x0 = q2s[c][nn], x1 = q2s[c][nn + 1], x2 = q2s[c][nn + 2];
    const float* wa = &w2t[c * 3 + 0][kh * 16];
    const float* wb = &w2t[c * 3 + 1][kh * 16];
    const float* wc = &w2t[c * 3 + 2][kh * 16];
#pragma unroll
    for (int i = 0; i < 16; ++i)
      acc[i] += wa[i] * x0 + wb[i] * x1 + wc[i] * x2;
  }
  const size_t row = ((size_t)b * NN + n0 + nn) * 32;
  u16x8 qo, ko;
#pragma unroll
  for (int i = 0; i < 8; ++i) {
    qo[i] = f2b(acc[2 * i]);
    ko[i] = f2b(acc[2 * i + 1]);
  }
  *(u16x8*)(Qt + row + kh * 8) = qo;
  *(u16x8*)(Kt + row + kh * 8) = ko;
}

// ---------------------------------------------------------------------------
// spatial mean of x per batch
__global__ __launch_bounds__(256) void k_spatial1(const float* __restrict__ x,
                                                  float* __restrict__ part) {
  const int b = blockIdx.y;
  const size_t off = (size_t)b * CC * NN + (size_t)blockIdx.x * 16384;
  float s = 0.f;
  for (int i = threadIdx.x; i < 16384; i += 256) s += x[off + i];
  __shared__ float red[256];
  red[threadIdx.x] = s;
  __syncthreads();
  for (int d = 128; d > 0; d >>= 1) {
    if (threadIdx.x < d) red[threadIdx.x] += red[threadIdx.x + d];
    __syncthreads();
  }
  if (threadIdx.x == 0) part[b * 64 + blockIdx.x] = red[0];
}

__global__ void k_spatial2(const float* __restrict__ part, float* __restrict__ spatial) {
  const int t = threadIdx.x;
  const int b = t >> 6, i = t & 63;
  float s = part[b * 64 + i];
  for (int d = 32; d > 0; d >>= 1) s += __shfl_down(s, d, 64);
  if (i == 0) spatial[b] = s * (1.0f / ((float)CC * NN));
}

// ---------------------------------------------------------------------------
// MFMA column exp-sum: psum[b][seg][m] = sum_{n in seg} exp(S[b][n][m])
__global__ __launch_bounds__(512) void k_colstatm(const unsigned short* __restrict__ Qt,
    const unsigned short* __restrict__ Kt, float* __restrict__ psum) {
  __shared__ float CS[2][4][64];
  const int m0 = blockIdx.x * 64, seg = blockIdx.y;
  const int t = threadIdx.x;
  const int w = t >> 6, l = t & 63;
  const int lo = l & 15, hi = l >> 4;
  const int mt = w & 3, nt2 = w >> 2;
  const f32x4 zero4 = (f32x4){0.f, 0.f, 0.f, 0.f};
  short8 kf[4];
#pragma unroll
  for (int bb = 0; bb < 4; ++bb)
    kf[bb] = *(const short8*)(Kt + ((size_t)(bb * NN + m0 + mt * 16 + lo)) * 32 + hi * 8);
  float colacc[4] = {0.f, 0.f, 0.f, 0.f};
  for (int ch = 0; ch < 8; ++ch) {
    const int nb = seg * 512 + ch * 64;
    short8 qf[2][4];
#pragma unroll
    for (int pos = 0; pos < 2; ++pos)
#pragma unroll
      for (int bb = 0; bb < 4; ++bb)
        qf[pos][bb] = *(const short8*)(Qt + ((size_t)(bb * NN + nb + (nt2 * 2 + pos) * 16 + lo)) * 32 + hi * 8);
#pragma unroll
    for (int pos = 0; pos < 2; ++pos) {
#pragma unroll
      for (int bb = 0; bb < 4; ++bb) {
        const f32x4 s = __builtin_amdgcn_mfma_f32_16x16x32_bf16(qf[pos][bb], kf[bb], zero4, 0, 0, 0);
#pragma unroll
        for (int r = 0; r < 4; ++r) colacc[bb] += __expf(fminf(s[r], 60.f));
      }
    }
  }
#pragma unroll
  for (int bb = 0; bb < 4; ++bb) {
    colacc[bb] += __shfl_xor(colacc[bb], 16, 64);
    colacc[bb] += __shfl_xor(colacc[bb], 32, 64);
  }
  if (hi == 0) {
#pragma unroll
    for (int bb = 0; bb < 4; ++bb) CS[nt2][bb][mt * 16 + lo] = colacc[bb];
  }
  __syncthreads();
  if (t < 256) {
    const int bb = t >> 6, mm = t & 63;
    psum[((size_t)(bb * SEGS + seg)) * NN + m0 + mm] = CS[0][bb][mm] + CS[1][bb][mm];
  }
}

__global__ void k_rsum(const float* __restrict__ psum, float* __restrict__ rcs) {
  const int gid = blockIdx.x * 256 + threadIdx.x;  // B*N = 16384
  const int b = gid >> 12, m = gid & (NN - 1);
  float S = 0.f;
#pragma unroll
  for (int s = 0; s < SEGS; ++s) S += psum[((size_t)(b * SEGS + s)) * NN + m];
  rcs[gid] = 1.0f / S;
}

// ---------------------------------------------------------------------------
// Fused attention v6: grid (128 n-tiles, 4 b), 512 thr = 8 waves.
// Wave w: sub = w&1 (16-n subtile), sl = w>>1 (1024-m slice). Barrier-free
// main loop; two 16-m halves processed sequentially (register budget).
// End: staged LDS reduction over the 4 m-slices, then sl==0 waves do the
// gamma*mean + x residual epilogue into channels-last padded fusb.
__global__ __launch_bounds__(512, 4) void k_fused(const unsigned short* __restrict__ Qt,
    const unsigned short* __restrict__ Kt, const unsigned short* __restrict__ Vb,
    const float* __restrict__ x, const float* __restrict__ rcs,
    const float* __restrict__ gamma, const float* __restrict__ spatial,
    unsigned short* __restrict__ fusb) {
  __shared__ unsigned short As[8][16][40];   // per-wave [n16][m32+pad], 10 KB
  __shared__ float red[2][16][16][20];       // [sub][ct][lo][row(pad)], 40 KB
  const int b = blockIdx.y;
  const int n0 = blockIdx.x * 32;
  const int t = threadIdx.x;
  const int w = t >> 6, l = t & 63;
  const int lo = l & 15, hi = l >> 4;
  const int sub = w & 1, sl = w >> 1;
  const int nb = n0 + sub * 16;
  const f32x4 zero4 = (f32x4){0.f, 0.f, 0.f, 0.f};

  short8 qf[4];
#pragma unroll
  for (int bb = 0; bb < 4; ++bb)
    qf[bb] = *(const short8*)(Qt + ((size_t)(bb * NN + nb + lo)) * 32 + hi * 8);

  f32x4 acc[16];
#pragma unroll
  for (int ct = 0; ct < 16; ++ct) acc[ct] = zero4;

  const float* rcs_b = rcs + b * NN;
  unsigned short* Asw = &As[w][0][0];
  const unsigned short* vbase = Vb + ((size_t)(b * CC + lo)) * NN + hi * 8;
  const int mbase = sl * 1024;

#pragma unroll 1
  for (int ch = 0; ch < 32; ++ch) {
    const int m0 = mbase + ch * 32;
    // ---- two 16-m halves sequentially (keeps live regs under 128)
#pragma unroll
    for (int h = 0; h < 2; ++h) {
      const int m16 = m0 + h * 16;
      short8 kf[4];
#pragma unroll
      for (int bb = 0; bb < 4; ++bb)
        kf[bb] = *(const short8*)(Kt + ((size_t)(bb * NN + m16 + lo)) * 32 + hi * 8);
      f32x4 s[4];
#pragma unroll
      for (int bb = 0; bb < 4; ++bb)
        s[bb] = __builtin_amdgcn_mfma_f32_16x16x32_bf16(qf[bb], kf[bb], zero4, 0, 0, 0);
      const float rc = rcs_b[m16 + lo];
#pragma unroll
      for (int r = 0; r < 4; ++r) {
        const float e0 = __expf(fminf(s[0][r], 60.f));
        const float e1 = __expf(fminf(s[1][r], 60.f));
        const float e2 = __expf(fminf(s[2][r], 60.f));
        const float e3 = __expf(fminf(s[3][r], 60.f));
        const float eb = b == 0 ? e0 : (b == 1 ? e1 : (b == 2 ? e2 : e3));
        const float a = eb * (__builtin_amdgcn_rcpf(e0 + e1 + e2 + e3) + rc);
        Asw[(hi * 4 + r) * 40 + h * 16 + lo] = f2b(a);
      }
    }
    // ---- transpose read: lane (lo,hi) gets A[n=lo][m=hi*8..+7]
    const short8 af = *(const short8*)(Asw + lo * 40 + hi * 8);
    // ---- PV: acc[ct] covers c = ct*16 + hi*4+r, n = nb + lo
#pragma unroll
    for (int ct = 0; ct < 16; ++ct) {
      const short8 vf = *(const short8*)(vbase + (size_t)ct * 16 * NN + m0);
      acc[ct] = __builtin_amdgcn_mfma_f32_16x16x32_bf16(vf, af, acc[ct], 0, 0, 0);
    }
  }

  // ---- staged reduction over m-slices (sl 3 -> 2 -> 1 -> 0)
  if (sl == 3) {
#pragma unroll
    for (int ct = 0; ct < 16; ++ct)
      *(f32x4*)&red[sub][ct][lo][hi * 4] = acc[ct];
  }
  __syncthreads();
  if (sl == 2) {
#pragma unroll
    for (int ct = 0; ct < 16; ++ct) {
      f32x4 v = *(const f32x4*)&red[sub][ct][lo][hi * 4];
      *(f32x4*)&red[sub][ct][lo][hi * 4] = v + acc[ct];
    }
  }
  __syncthreads();
  if (sl == 1) {
#pragma unroll
    for (int ct = 0; ct < 16; ++ct) {
      f32x4 v = *(const f32x4*)&red[sub][ct][lo][hi * 4];
      *(f32x4*)&red[sub][ct][lo][hi * 4] = v + acc[ct];
    }
  }
  __syncthreads();
  if (sl == 0) {
    const float g = gamma[0] * spatial[b];
    const int n = nb + lo;
    const int iy = n >> 6, ix = n & 63;
    unsigned short* fb = fusb + (((size_t)(b * 66 + iy + 1)) * 66 + ix + 1) * 256;
#pragma unroll
    for (int ct = 0; ct < 16; ++ct) {
      const f32x4 v = *(const f32x4*)&red[sub][ct][lo][hi * 4];
      u16x4 o;
#pragma unroll
      for (int r = 0; r < 4; ++r) {
        const int c = ct * 16 + hi * 4 + r;
        const float fin = acc[ct][r] + v[r];
        o[r] = f2b(g * fin + x[((size_t)(b * CC + c)) * NN + n]);
      }
      *(u16x4*)(fb + ct * 16 + hi * 4) = o;
    }
  }
}

// ---------------------------------------------------------------------------
// weight transform: wbf[p][tap][o][ic] (bf16, ic contiguous)
__global__ void k_wprep(const float* __restrict__ w_co, unsigned short* __restrict__ wbf) {
  const int gid = blockIdx.x * 256 + threadIdx.x;
  const int ic = gid & 255;
  const int o = (gid >> 8) & 127;
  const int tap = (gid >> 15) & 3;
  const int p = gid >> 17;
  const int py = p >> 1, px = p & 1;
  const int tyi = tap >> 1, txi = tap & 1;
  const int ky = py + 2 * tyi, kx = px + 2 * txi;
  wbf[gid] = f2b(w_co[(ic * 128 + o) * 16 + (3 - ky) * 4 + (3 - kx)]);
}

// ---------------------------------------------------------------------------
// MFMA transposed conv
__global__ __launch_bounds__(512) void k_deconv(const unsigned short* __restrict__ fusb,
    const unsigned short* __restrict__ wbf, const float* __restrict__ b_co,
    float* __restrict__ out) {
  const int bp = blockIdx.y;
  const int b = bp >> 2, py = (bp >> 1) & 1, px = bp & 1;
  const int t = threadIdx.x;
  const int w = t >> 6, l = t & 63;
  const int lo = l & 15, hi = l >> 4;
  const int wm = w & 1, wrow = w >> 1;
  const int iy = blockIdx.x * 4 + wrow;
  f32x4 acc[4][4];
#pragma unroll
  for (int mt = 0; mt < 4; ++mt)
#pragma unroll
    for (int nt = 0; nt < 4; ++nt) acc[mt][nt] = (f32x4){0.f, 0.f, 0.f, 0.f};
  const unsigned short* wp_base = wbf + (size_t)(bp & 3) * 4 * 128 * 256;
  for (int tap = 0; tap < 4; ++tap) {
    const int tyi = tap >> 1, txi = tap & 1;
    const int dy = py + tyi - 1, dx = px + txi - 1;
    const unsigned short* wtap = wp_base + (size_t)tap * 128 * 256 + (size_t)(wm * 64 + lo) * 256 + hi * 8;
    const unsigned short* fb = fusb + ((size_t)(b * 66 + iy + dy + 1) * 66 + (lo + dx + 1)) * 256 + hi * 8;
#pragma unroll
    for (int ic0 = 0; ic0 < 256; ic0 += 32) {
      short8 a[4], bf[4];
#pragma unroll
      for (int mt = 0; mt < 4; ++mt) a[mt] = *(const short8*)(wtap + mt * 16 * 256 + ic0);
#pragma unroll
      for (int nt = 0; nt < 4; ++nt) bf[nt] = *(const short8*)(fb + nt * 16 * 256 + ic0);
#pragma unroll
      for (int mt = 0; mt < 4; ++mt)
#pragma unroll
        for (int nt = 0; nt < 4; ++nt)
          acc[mt][nt] = __builtin_amdgcn_mfma_f32_16x16x32_bf16(a[mt], bf[nt], acc[mt][nt], 0, 0, 0);
    }
  }
  const int y = 2 * iy + py;
#pragma unroll
  for (int mt = 0; mt < 4; ++mt) {
#pragma unroll
    for (int nt = 0; nt < 4; ++nt) {
#pragma unroll
      for (int r = 0; r < 4; ++r) {
        const int o = wm * 64 + mt * 16 + hi * 4 + r;
        const int xx = 2 * (nt * 16 + lo) + px;
        out[(((size_t)(b * OCH + o)) * 128 + y) * 128 + xx] = acc[mt][nt][r] + b_co[o];
      }
    }
  }
}

// ---------------------------------------------------------------------------
extern "C" void kernel_launch(void* const* d_in, const int* in_sizes, int n_in,
                              void* d_out, int out_size, void* d_ws, size_t ws_size,
                              hipStream_t stream) {
  const float* x     = (const float*)d_in[0];
  const float* wq    = (const float*)d_in[1];
  const float* bq    = (const float*)d_in[2];
  const float* wv    = (const float*)d_in[3];
  const float* bv    = (const float*)d_in[4];
  const float* w1    = (const float*)d_in[5];
  const float* b1    = (const float*)d_in[6];
  const float* w2    = (const float*)d_in[7];
  const float* b2    = (const float*)d_in[8];
  const float* gamma = (const float*)d_in[9];
  const float* w_co  = (const float*)d_in[10];
  const float* b_co  = (const float*)d_in[11];
  float* out = (float*)d_out;
  (void)in_sizes; (void)n_in; (void)out_size; (void)ws_size;

  char* p = (char*)d_ws;
  unsigned short* xt      = (unsigned short*)p; p += (size_t)BN * NN * CC * 2;      // 8.4 MB
  unsigned short* q1b     = (unsigned short*)p; p += (size_t)BN * CC * NN * 2;      // 8.4 MB
  float*          q2      = (float*)p;          p += (size_t)BN * CR * NN * 4;      // 2 MB
  float*          psum    = (float*)p;          p += (size_t)BN * SEGS * NN * 4;    // 0.5 MB
  float*          part    = (float*)p;          p += (size_t)256 * 4;
  unsigned short* Qt      = (unsigned short*)p; p += (size_t)BN * NN * 32 * 2;      // 1 MB
  unsigned short* Kt      = (unsigned short*)p; p += (size_t)BN * NN * 32 * 2;      // 1 MB
  unsigned short* Vb      = (unsigned short*)p; p += (size_t)BN * CC * NN * 2;      // 8.4 MB
  float*          rcs     = (float*)p;          p += (size_t)BN * NN * 4;
  float*          spatial = (float*)p;          p += 256;
  unsigned short* wqb     = (unsigned short*)p; p += (size_t)CC * CC * 2;
  unsigned short* wvb     = (unsigned short*)p; p += (size_t)CC * CC * 2;
  unsigned short* wbf     = (unsigned short*)p; p += (size_t)4 * 4 * 128 * 256 * 2; // 1 MB
  unsigned short* fusb    = (unsigned short*)p;                                     // 8.9 MB

  // border-zero padded fusion buffer
  hipMemsetAsync(fusb, 0, (size_t)BN * 66 * 66 * 256 * 2, stream);

  k_wcast<<<dim3(64, 2), 256, 0, stream>>>(wq, wv, wqb, wvb);
  k_xt<<<dim3(64, 4, 4), 256, 0, stream>>>(x, xt);
  k_projm<<<dim3(128, 4, 2), 256, 0, stream>>>(xt, wqb, bq, wvb, bv, q1b, Vb);
  k_adj1<<<dim3(2048), 256, 0, stream>>>(q1b, w1, b1, q2);
  k_adj2<<<dim3(64, 4), 256, 0, stream>>>(q2, w2, b2, Qt, Kt);
  k_spatial1<<<dim3(64, 4), 256, 0, stream>>>(x, part);
  k_spatial2<<<dim3(1), 256, 0, stream>>>(part, spatial);
  k_colstatm<<<dim3(64, SEGS), 512, 0, stream>>>(Qt, Kt, psum);
  k_rsum<<<dim3(64), 256, 0, stream>>>(psum, rcs);
  k_wprep<<<dim3(2048), 256, 0, stream>>>(w_co, wbf);
  k_fused<<<dim3(128, 4), 512, 0, stream>>>(Qt, Kt, Vb, x, rcs, gamma, spatial, fusb);
  k_deconv<<<dim3(16, 16), 512, 0, stream>>>(fusb, wbf, b_co, out);
}

// Round 7
// 486.551 us; speedup vs baseline: 1.0640x; 1.0640x over previous
//
#include <hip/hip_runtime.h>

#define BN 4
#define CC 256
#define NN 4096
#define CR 32
#define OCH 128
#define SEGS 8

typedef float f32x4 __attribute__((ext_vector_type(4)));
typedef short short8 __attribute__((ext_vector_type(8)));
typedef unsigned short u16x8 __attribute__((ext_vector_type(8)));
typedef unsigned short u16x4 __attribute__((ext_vector_type(4)));

__device__ __forceinline__ unsigned short f2b(float f) {
  unsigned u = __builtin_bit_cast(unsigned, f);
  u += 0x7fff + ((u >> 16) & 1);
  return (unsigned short)(u >> 16);
}
__device__ __forceinline__ float b2f(unsigned short h) {
  unsigned u = ((unsigned)h) << 16;
  return __builtin_bit_cast(float, u);
}

// ---------------------------------------------------------------------------
// cast wq / wv to bf16
__global__ __launch_bounds__(256) void k_wcast(const float* __restrict__ wq,
    const float* __restrict__ wv, unsigned short* __restrict__ wqb,
    unsigned short* __restrict__ wvb) {
  const int gid = (blockIdx.x * 256 + threadIdx.x) * 4;
  const float* src = blockIdx.y ? wv : wq;
  unsigned short* dst = blockIdx.y ? wvb : wqb;
  const float4 v = *(const float4*)(src + gid);
  u16x4 o; o[0] = f2b(v.x); o[1] = f2b(v.y); o[2] = f2b(v.z); o[3] = f2b(v.w);
  *(u16x4*)(dst + gid) = o;
}

// ---------------------------------------------------------------------------
// transpose+cast: x[b][c][n] f32 -> xt[b][n][c] bf16
__global__ __launch_bounds__(256) void k_xt(const float* __restrict__ x,
    unsigned short* __restrict__ xt) {
  __shared__ unsigned short T[64][65];
  const int b = blockIdx.z, c0 = blockIdx.y * 64, n0 = blockIdx.x * 64;
  const int t = threadIdx.x;
  for (int idx = t; idx < 4096; idx += 256) {
    int i = idx >> 6, j = idx & 63;
    T[i][j] = f2b(x[((size_t)(b * CC + c0 + i)) * NN + n0 + j]);
  }
  __syncthreads();
  for (int idx = t; idx < 4096; idx += 256) {
    int j = idx >> 6, i = idx & 63;
    xt[((size_t)(b * NN + n0 + j)) * CC + c0 + i] = T[i][j];
  }
}

// ---------------------------------------------------------------------------
// MFMA projection GEMM: out[b][c][n] = bias[c] + sum_j W[c][j] xt[b][n][j]
__global__ __launch_bounds__(256) void k_projm(const unsigned short* __restrict__ xt,
    const unsigned short* __restrict__ wqb, const float* __restrict__ bq,
    const unsigned short* __restrict__ wvb, const float* __restrict__ bv,
    unsigned short* __restrict__ q1b, unsigned short* __restrict__ Vb) {
  const int b = blockIdx.y, n0 = blockIdx.x * 32, which = blockIdx.z;
  const unsigned short* W = which ? wvb : wqb;
  const float* bias = which ? bv : bq;
  unsigned short* out = which ? Vb : q1b;
  const int t = threadIdx.x;
  const int w = t >> 6, l = t & 63;
  const int lo = l & 15, hi = l >> 4;
  const int oc0 = w * 64;
  f32x4 acc[4][2];
#pragma unroll
  for (int ct = 0; ct < 4; ++ct)
#pragma unroll
    for (int nt = 0; nt < 2; ++nt) acc[ct][nt] = (f32x4){0.f, 0.f, 0.f, 0.f};
  const unsigned short* wb = W + (size_t)(oc0 + lo) * CC + hi * 8;
  const unsigned short* xb = xt + ((size_t)(b * NN + n0 + lo)) * CC + hi * 8;
#pragma unroll
  for (int k0 = 0; k0 < CC; k0 += 32) {
    short8 aw[4], bx[2];
#pragma unroll
    for (int ct = 0; ct < 4; ++ct) aw[ct] = *(const short8*)(wb + ct * 16 * CC + k0);
#pragma unroll
    for (int nt = 0; nt < 2; ++nt) bx[nt] = *(const short8*)(xb + nt * 16 * CC + k0);
#pragma unroll
    for (int ct = 0; ct < 4; ++ct)
#pragma unroll
      for (int nt = 0; nt < 2; ++nt)
        acc[ct][nt] = __builtin_amdgcn_mfma_f32_16x16x32_bf16(aw[ct], bx[nt], acc[ct][nt], 0, 0, 0);
  }
#pragma unroll
  for (int ct = 0; ct < 4; ++ct) {
#pragma unroll
    for (int r = 0; r < 4; ++r) {
      const int c = oc0 + ct * 16 + hi * 4 + r;
      const float bvv = bias[c];
#pragma unroll
      for (int nt = 0; nt < 2; ++nt)
        out[((size_t)(b * CC + c)) * NN + n0 + nt * 16 + lo] = f2b(acc[ct][nt][r] + bvv);
    }
  }
}

// ---------------------------------------------------------------------------
// grouped conv1d (bf16 in, f32 out), vectorized: thread = 8 consecutive n
__global__ __launch_bounds__(256) void k_adj1(const unsigned short* __restrict__ q1,
    const float* __restrict__ w1, const float* __restrict__ b1,
    float* __restrict__ q2) {
  const int gid = blockIdx.x * 256 + threadIdx.x;   // B*32*(N/8) = 65536
  const int n8 = gid & 511;
  const int o = (gid >> 9) & 31;
  const int b = gid >> 14;
  const int n0 = n8 * 8;
  const unsigned short* base = q1 + ((size_t)b * CC + o * 8) * NN;
  float accv[8];
  const float bias = b1[o];
#pragma unroll
  for (int j = 0; j < 8; ++j) accv[j] = bias;
#pragma unroll
  for (int i = 0; i < 8; ++i) {
    const unsigned short* r = base + (size_t)i * NN;
    const u16x8 v = *(const u16x8*)(r + n0);
    float f[10];
    f[0] = (n0 > 0) ? b2f(r[n0 - 1]) : 0.f;
#pragma unroll
    for (int j = 0; j < 8; ++j) f[j + 1] = b2f(v[j]);
    f[9] = (n0 + 8 < NN) ? b2f(r[n0 + 8]) : 0.f;
    const float wa = w1[o * 24 + i * 3 + 0];
    const float wb = w1[o * 24 + i * 3 + 1];
    const float wc = w1[o * 24 + i * 3 + 2];
#pragma unroll
    for (int j = 0; j < 8; ++j) accv[j] += wa * f[j] + wb * f[j + 1] + wc * f[j + 2];
  }
  float4* dst = (float4*)&q2[((size_t)b * CR + o) * NN + n0];
  dst[0] = make_float4(accv[0], accv[1], accv[2], accv[3]);
  dst[1] = make_float4(accv[4], accv[5], accv[6], accv[7]);
}

// ---------------------------------------------------------------------------
// conv1d 32->64ch, writes bf16 TRANSPOSED Qt[b][n][32], Kt[b][n][32]
__global__ __launch_bounds__(256) void k_adj2(const float* __restrict__ q2,
    const float* __restrict__ w2, const float* __restrict__ b2,
    unsigned short* __restrict__ Qt, unsigned short* __restrict__ Kt) {
  __shared__ float q2s[32][66];
  __shared__ float w2t[96][64];
  __shared__ float b2s[64];
  const int b = blockIdx.y, n0 = blockIdx.x * 64;
  const int t = threadIdx.x;
  for (int idx = t; idx < 32 * 66; idx += 256) {
    int c = idx / 66, nn = idx % 66;
    int n = n0 + nn - 1;
    q2s[c][nn] = (n >= 0 && n < NN) ? q2[((size_t)b * CR + c) * NN + n] : 0.f;
  }
  for (int idx = t; idx < 96 * 64; idx += 256) {
    int k = idx & 63, ct = idx >> 6;
    w2t[ct][k] = w2[k * 96 + ct];
  }
  if (t < 64) b2s[t] = b2[t];
  __syncthreads();
  const int nn = t & 63, kh = t >> 6;
  float acc[16];
#pragma unroll
  for (int i = 0; i < 16; ++i) acc[i] = b2s[kh * 16 + i];
  for (int c = 0; c < 32; ++c) {
    const float x0 = q2s[c][nn], x1 = q2s[c][nn + 1], x2 = q2s[c][nn + 2];
    const float* wa = &w2t[c * 3 + 0][kh * 16];
    const float* wb = &w2t[c * 3 + 1][kh * 16];
    const float* wc = &w2t[c * 3 + 2][kh * 16];
#pragma unroll
    for (int i = 0; i < 16; ++i)
      acc[i] += wa[i] * x0 + wb[i] * x1 + wc[i] * x2;
  }
  const size_t row = ((size_t)b * NN + n0 + nn) * 32;
  u16x8 qo, ko;
#pragma unroll
  for (int i = 0; i < 8; ++i) {
    qo[i] = f2b(acc[2 * i]);
    ko[i] = f2b(acc[2 * i + 1]);
  }
  *(u16x8*)(Qt + row + kh * 8) = qo;
  *(u16x8*)(Kt + row + kh * 8) = ko;
}

// ---------------------------------------------------------------------------
// spatial mean of x per batch
__global__ __launch_bounds__(256) void k_spatial1(const float* __restrict__ x,
                                                  float* __restrict__ part) {
  const int b = blockIdx.y;
  const size_t off = (size_t)b * CC * NN + (size_t)blockIdx.x * 16384;
  float s = 0.f;
  for (int i = threadIdx.x; i < 16384; i += 256) s += x[off + i];
  __shared__ float red[256];
  red[threadIdx.x] = s;
  __syncthreads();
  for (int d = 128; d > 0; d >>= 1) {
    if (threadIdx.x < d) red[threadIdx.x] += red[threadIdx.x + d];
    __syncthreads();
  }
  if (threadIdx.x == 0) part[b * 64 + blockIdx.x] = red[0];
}

__global__ void k_spatial2(const float* __restrict__ part, float* __restrict__ spatial) {
  const int t = threadIdx.x;
  const int b = t >> 6, i = t & 63;
  float s = part[b * 64 + i];
  for (int d = 32; d > 0; d >>= 1) s += __shfl_down(s, d, 64);
  if (i == 0) spatial[b] = s * (1.0f / ((float)CC * NN));
}

// ---------------------------------------------------------------------------
// MFMA column exp-sum: psum[b][seg][m] = sum_{n in seg} exp(S[b][n][m])
__global__ __launch_bounds__(512) void k_colstatm(const unsigned short* __restrict__ Qt,
    const unsigned short* __restrict__ Kt, float* __restrict__ psum) {
  __shared__ float CS[2][4][64];
  const int m0 = blockIdx.x * 64, seg = blockIdx.y;
  const int t = threadIdx.x;
  const int w = t >> 6, l = t & 63;
  const int lo = l & 15, hi = l >> 4;
  const int mt = w & 3, nt2 = w >> 2;
  const f32x4 zero4 = (f32x4){0.f, 0.f, 0.f, 0.f};
  short8 kf[4];
#pragma unroll
  for (int bb = 0; bb < 4; ++bb)
    kf[bb] = *(const short8*)(Kt + ((size_t)(bb * NN + m0 + mt * 16 + lo)) * 32 + hi * 8);
  float colacc[4] = {0.f, 0.f, 0.f, 0.f};
  for (int ch = 0; ch < 8; ++ch) {
    const int nb = seg * 512 + ch * 64;
    short8 qf[2][4];
#pragma unroll
    for (int pos = 0; pos < 2; ++pos)
#pragma unroll
      for (int bb = 0; bb < 4; ++bb)
        qf[pos][bb] = *(const short8*)(Qt + ((size_t)(bb * NN + nb + (nt2 * 2 + pos) * 16 + lo)) * 32 + hi * 8);
#pragma unroll
    for (int pos = 0; pos < 2; ++pos) {
#pragma unroll
      for (int bb = 0; bb < 4; ++bb) {
        const f32x4 s = __builtin_amdgcn_mfma_f32_16x16x32_bf16(qf[pos][bb], kf[bb], zero4, 0, 0, 0);
#pragma unroll
        for (int r = 0; r < 4; ++r) colacc[bb] += __expf(fminf(s[r], 60.f));
      }
    }
  }
#pragma unroll
  for (int bb = 0; bb < 4; ++bb) {
    colacc[bb] += __shfl_xor(colacc[bb], 16, 64);
    colacc[bb] += __shfl_xor(colacc[bb], 32, 64);
  }
  if (hi == 0) {
#pragma unroll
    for (int bb = 0; bb < 4; ++bb) CS[nt2][bb][mt * 16 + lo] = colacc[bb];
  }
  __syncthreads();
  if (t < 256) {
    const int bb = t >> 6, mm = t & 63;
    psum[((size_t)(bb * SEGS + seg)) * NN + m0 + mm] = CS[0][bb][mm] + CS[1][bb][mm];
  }
}

__global__ void k_rsum(const float* __restrict__ psum, float* __restrict__ rcs) {
  const int gid = blockIdx.x * 256 + threadIdx.x;  // B*N = 16384
  const int b = gid >> 12, m = gid & (NN - 1);
  float S = 0.f;
#pragma unroll
  for (int s = 0; s < SEGS; ++s) S += psum[((size_t)(b * SEGS + s)) * NN + m];
  rcs[gid] = 1.0f / S;
}

// ---------------------------------------------------------------------------
// A-generation: S via MFMA (once per (n,m)), double softmax, write A bf16
// A layout: [4][stripeN][NN] m-contig.  grid (stripeN/64, 8 m-segs), 512 thr.
__global__ __launch_bounds__(512) void k_agen(const unsigned short* __restrict__ Qt,
    const unsigned short* __restrict__ Kt, const float* __restrict__ rcs,
    unsigned short* __restrict__ A, int n_base, int stripeN) {
  __shared__ unsigned short As[4][64][72];
  const int n0 = n_base + blockIdx.x * 64, mseg = blockIdx.y;
  const int t = threadIdx.x;
  const int w = t >> 6, l = t & 63;
  const int lo = l & 15, hi = l >> 4;
  const int mt = w & 3, nt2 = w >> 2;
  const f32x4 zero4 = (f32x4){0.f, 0.f, 0.f, 0.f};
  short8 qf[2][4];
#pragma unroll
  for (int pos = 0; pos < 2; ++pos)
#pragma unroll
    for (int bb = 0; bb < 4; ++bb)
      qf[pos][bb] = *(const short8*)(Qt + ((size_t)(bb * NN + n0 + (nt2 * 2 + pos) * 16 + lo)) * 32 + hi * 8);
  for (int ch = 0; ch < 8; ++ch) {
    const int m0 = mseg * 512 + ch * 64;
    const int mS = m0 + mt * 16 + lo;
    short8 kf[4];
#pragma unroll
    for (int bb = 0; bb < 4; ++bb)
      kf[bb] = *(const short8*)(Kt + ((size_t)(bb * NN + mS)) * 32 + hi * 8);
    f32x4 s[2][4];
#pragma unroll
    for (int pos = 0; pos < 2; ++pos)
#pragma unroll
      for (int bb = 0; bb < 4; ++bb)
        s[pos][bb] = __builtin_amdgcn_mfma_f32_16x16x32_bf16(qf[pos][bb], kf[bb], zero4, 0, 0, 0);
    float rc[4];
#pragma unroll
    for (int bb = 0; bb < 4; ++bb) rc[bb] = rcs[bb * NN + mS];
    unsigned short av[2][4][4];
#pragma unroll
    for (int pos = 0; pos < 2; ++pos) {
#pragma unroll
      for (int r = 0; r < 4; ++r) {
        float e[4];
#pragma unroll
        for (int bb = 0; bb < 4; ++bb) e[bb] = __expf(fminf(s[pos][bb][r], 60.f));
        const float rden = __builtin_amdgcn_rcpf(e[0] + e[1] + e[2] + e[3]);
#pragma unroll
        for (int bb = 0; bb < 4; ++bb) av[pos][r][bb] = f2b(e[bb] * (rden + rc[bb]));
      }
    }
    __syncthreads();   // previous copy-out done
#pragma unroll
    for (int pos = 0; pos < 2; ++pos) {
      const int nl0 = (nt2 * 2 + pos) * 16 + hi * 4;
      const int ml = mt * 16 + lo;
#pragma unroll
      for (int r = 0; r < 4; ++r)
#pragma unroll
        for (int bb = 0; bb < 4; ++bb) As[bb][nl0 + r][ml] = av[pos][r][bb];
    }
    __syncthreads();
    // coalesced copy-out: 2048 u16x8 units
#pragma unroll
    for (int q = 0; q < 4; ++q) {
      const int u = t + q * 512;
      const int bb = u >> 9, rest = u & 511;
      const int nl = rest >> 3, mg = (rest & 7) * 8;
      u16x8 v = *(const u16x8*)&As[bb][nl][mg];
      *(u16x8*)(A + ((size_t)bb * stripeN + (n0 - n_base) + nl) * NN + m0 + mg) = v;
    }
  }
}

// ---------------------------------------------------------------------------
// PV GEMM + epilogue, high-parallelism version: 16-n tiles, 4 waves = 4 c-groups.
// grid (stripeN/16, 4 b), 256 thr.  acc = 64c x 16n per wave.
__global__ __launch_bounds__(256, 4) void k_pv(const unsigned short* __restrict__ Vb,
    const unsigned short* __restrict__ A, const float* __restrict__ x,
    const float* __restrict__ gamma, const float* __restrict__ spatial,
    unsigned short* __restrict__ fusb, int n_base, int stripeN) {
  __shared__ unsigned short Fs[16][264];
  const int b = blockIdx.y;
  const int nloc0 = blockIdx.x * 16;
  const int t = threadIdx.x;
  const int w = t >> 6, l = t & 63;
  const int lo = l & 15, hi = l >> 4;
  const int cg = w;                       // c base = cg*64
  const f32x4 zero4 = (f32x4){0.f, 0.f, 0.f, 0.f};
  f32x4 acc[4];
#pragma unroll
  for (int ct = 0; ct < 4; ++ct) acc[ct] = zero4;
  const unsigned short* vb = Vb + ((size_t)(b * CC + cg * 64 + lo)) * NN + hi * 8;
  const unsigned short* ab = A + ((size_t)b * stripeN + nloc0 + lo) * NN + hi * 8;
#pragma unroll 4
  for (int m0 = 0; m0 < NN; m0 += 32) {
    const short8 af = *(const short8*)(ab + m0);
    short8 vf[4];
#pragma unroll
    for (int ct = 0; ct < 4; ++ct) vf[ct] = *(const short8*)(vb + (size_t)ct * 16 * NN + m0);
#pragma unroll
    for (int ct = 0; ct < 4; ++ct)
      acc[ct] = __builtin_amdgcn_mfma_f32_16x16x32_bf16(vf[ct], af, acc[ct], 0, 0, 0);
  }
  // epilogue: gamma*mean*acc + x -> bf16, staged via LDS for coalesced store
  const float g = gamma[0] * spatial[b];
  const int n_abs0 = n_base + nloc0;
#pragma unroll
  for (int ct = 0; ct < 4; ++ct) {
    u16x4 o4;
#pragma unroll
    for (int r = 0; r < 4; ++r) {
      const int c = cg * 64 + ct * 16 + hi * 4 + r;
      const float xv = x[((size_t)(b * CC + c)) * NN + n_abs0 + lo];
      o4[r] = f2b(g * acc[ct][r] + xv);
    }
    *(u16x4*)&Fs[lo][cg * 64 + ct * 16 + hi * 4] = o4;
  }
  __syncthreads();
  const int iy = n_abs0 >> 6, ix0 = n_abs0 & 63;   // 16-aligned tile, same row
  unsigned short* fb = fusb + (((size_t)(b * 66 + iy + 1)) * 66 + ix0 + 1) * 256;
#pragma unroll
  for (int q = 0; q < 2; ++q) {
    const int u = t + q * 256;               // 0..511
    const int nl = u >> 5, c0 = (u & 31) * 8;
    *(u16x8*)(fb + (size_t)nl * 256 + c0) = *(const u16x8*)&Fs[nl][c0];
  }
}

// ---------------------------------------------------------------------------
// weight transform: wbf[p][tap][o][ic] (bf16, ic contiguous)
__global__ void k_wprep(const float* __restrict__ w_co, unsigned short* __restrict__ wbf) {
  const int gid = blockIdx.x * 256 + threadIdx.x;
  const int ic = gid & 255;
  const int o = (gid >> 8) & 127;
  const int tap = (gid >> 15) & 3;
  const int p = gid >> 17;
  const int py = p >> 1, px = p & 1;
  const int tyi = tap >> 1, txi = tap & 1;
  const int ky = py + 2 * tyi, kx = px + 2 * txi;
  wbf[gid] = f2b(w_co[(ic * 128 + o) * 16 + (3 - ky) * 4 + (3 - kx)]);
}

// ---------------------------------------------------------------------------
// MFMA transposed conv
__global__ __launch_bounds__(512) void k_deconv(const unsigned short* __restrict__ fusb,
    const unsigned short* __restrict__ wbf, const float* __restrict__ b_co,
    float* __restrict__ out) {
  const int bp = blockIdx.y;
  const int b = bp >> 2, py = (bp >> 1) & 1, px = bp & 1;
  const int t = threadIdx.x;
  const int w = t >> 6, l = t & 63;
  const int lo = l & 15, hi = l >> 4;
  const int wm = w & 1, wrow = w >> 1;
  const int iy = blockIdx.x * 4 + wrow;
  f32x4 acc[4][4];
#pragma unroll
  for (int mt = 0; mt < 4; ++mt)
#pragma unroll
    for (int nt = 0; nt < 4; ++nt) acc[mt][nt] = (f32x4){0.f, 0.f, 0.f, 0.f};
  const unsigned short* wp_base = wbf + (size_t)(bp & 3) * 4 * 128 * 256;
  for (int tap = 0; tap < 4; ++tap) {
    const int tyi = tap >> 1, txi = tap & 1;
    const int dy = py + tyi - 1, dx = px + txi - 1;
    const unsigned short* wtap = wp_base + (size_t)tap * 128 * 256 + (size_t)(wm * 64 + lo) * 256 + hi * 8;
    const unsigned short* fb = fusb + ((size_t)(b * 66 + iy + dy + 1) * 66 + (lo + dx + 1)) * 256 + hi * 8;
#pragma unroll
    for (int ic0 = 0; ic0 < 256; ic0 += 32) {
      short8 a[4], bf[4];
#pragma unroll
      for (int mt = 0; mt < 4; ++mt) a[mt] = *(const short8*)(wtap + mt * 16 * 256 + ic0);
#pragma unroll
      for (int nt = 0; nt < 4; ++nt) bf[nt] = *(const short8*)(fb + nt * 16 * 256 + ic0);
#pragma unroll
      for (int mt = 0; mt < 4; ++mt)
#pragma unroll
        for (int nt = 0; nt < 4; ++nt)
          acc[mt][nt] = __builtin_amdgcn_mfma_f32_16x16x32_bf16(a[mt], bf[nt], acc[mt][nt], 0, 0, 0);
    }
  }
  const int y = 2 * iy + py;
#pragma unroll
  for (int mt = 0; mt < 4; ++mt) {
#pragma unroll
    for (int nt = 0; nt < 4; ++nt) {
#pragma unroll
      for (int r = 0; r < 4; ++r) {
        const int o = wm * 64 + mt * 16 + hi * 4 + r;
        const int xx = 2 * (nt * 16 + lo) + px;
        out[(((size_t)(b * OCH + o)) * 128 + y) * 128 + xx] = acc[mt][nt][r] + b_co[o];
      }
    }
  }
}

// ---------------------------------------------------------------------------
extern "C" void kernel_launch(void* const* d_in, const int* in_sizes, int n_in,
                              void* d_out, int out_size, void* d_ws, size_t ws_size,
                              hipStream_t stream) {
  const float* x     = (const float*)d_in[0];
  const float* wq    = (const float*)d_in[1];
  const float* bq    = (const float*)d_in[2];
  const float* wv    = (const float*)d_in[3];
  const float* bv    = (const float*)d_in[4];
  const float* w1    = (const float*)d_in[5];
  const float* b1    = (const float*)d_in[6];
  const float* w2    = (const float*)d_in[7];
  const float* b2    = (const float*)d_in[8];
  const float* gamma = (const float*)d_in[9];
  const float* w_co  = (const float*)d_in[10];
  const float* b_co  = (const float*)d_in[11];
  float* out = (float*)d_out;
  (void)in_sizes; (void)n_in; (void)out_size;

  // --- survivor region sizes (bytes) ---
  const size_t SZ_QT   = (size_t)BN * NN * 32 * 2;        // 1 MB
  const size_t SZ_VB   = (size_t)BN * CC * NN * 2;        // 8.4 MB
  const size_t SZ_RCS  = (size_t)BN * NN * 4;
  const size_t SZ_W    = (size_t)CC * CC * 2;             // 128 KB
  const size_t SZ_WBF  = (size_t)4 * 4 * 128 * 256 * 2;   // 1 MB
  const size_t SZ_FUSB = (size_t)BN * 66 * 66 * 256 * 2;  // 8.9 MB
  const size_t SURV = SZ_QT * 2 + SZ_VB + SZ_RCS + 256 + SZ_W * 2 + SZ_WBF + SZ_FUSB + 4096;

  // region0 holds early-dead temps, later overwritten by A
  const size_t SZ_XT  = (size_t)BN * NN * CC * 2;   // 8.4 MB
  const size_t SZ_Q1  = (size_t)BN * CC * NN * 2;   // 8.4 MB
  const size_t SZ_Q2  = (size_t)BN * CR * NN * 4;   // 2 MB
  const size_t SZ_PS  = (size_t)BN * SEGS * NN * 4; // 0.5 MB
  const size_t TEMPS  = SZ_XT + SZ_Q1 + SZ_Q2 + SZ_PS + 2048;

  int stripes;
  size_t a_bytes_full = (size_t)BN * NN * NN * 2;   // 134 MB
  if (ws_size >= a_bytes_full + SURV + (1 << 20)) stripes = 1;
  else if (ws_size >= a_bytes_full / 4 + SURV + (1 << 20) && a_bytes_full / 4 >= TEMPS) stripes = 4;
  else stripes = 8;
  const int stripeN = NN / stripes;
  const size_t R0 = (((size_t)BN * stripeN * NN * 2 > TEMPS) ? (size_t)BN * stripeN * NN * 2 : TEMPS);

  char* p0 = (char*)d_ws;
  unsigned short* A    = (unsigned short*)p0;
  unsigned short* xt   = (unsigned short*)p0;
  unsigned short* q1b  = (unsigned short*)(p0 + SZ_XT);
  float*          q2   = (float*)(p0 + SZ_XT + SZ_Q1);
  float*          psum = (float*)(p0 + SZ_XT + SZ_Q1 + SZ_Q2);
  float*          part = (float*)(p0 + SZ_XT + SZ_Q1 + SZ_Q2 + SZ_PS);

  char* ps = p0 + R0;
  unsigned short* Qt      = (unsigned short*)ps;            ps += SZ_QT;
  unsigned short* Kt      = (unsigned short*)ps;            ps += SZ_QT;
  unsigned short* Vb      = (unsigned short*)ps;            ps += SZ_VB;
  float*          rcs     = (float*)ps;                     ps += SZ_RCS;
  float*          spatial = (float*)ps;                     ps += 256;
  unsigned short* wqb     = (unsigned short*)ps;            ps += SZ_W;
  unsigned short* wvb     = (unsigned short*)ps;            ps += SZ_W;
  unsigned short* wbf     = (unsigned short*)ps;            ps += SZ_WBF;
  unsigned short* fusb    = (unsigned short*)ps;

  // border-zero padded fusion buffer
  hipMemsetAsync(fusb, 0, SZ_FUSB, stream);

  k_wcast<<<dim3(64, 2), 256, 0, stream>>>(wq, wv, wqb, wvb);
  k_xt<<<dim3(64, 4, 4), 256, 0, stream>>>(x, xt);
  k_projm<<<dim3(128, 4, 2), 256, 0, stream>>>(xt, wqb, bq, wvb, bv, q1b, Vb);
  k_adj1<<<dim3(256), 256, 0, stream>>>(q1b, w1, b1, q2);
  k_adj2<<<dim3(64, 4), 256, 0, stream>>>(q2, w2, b2, Qt, Kt);
  k_spatial1<<<dim3(64, 4), 256, 0, stream>>>(x, part);
  k_spatial2<<<dim3(1), 256, 0, stream>>>(part, spatial);
  k_colstatm<<<dim3(64, SEGS), 512, 0, stream>>>(Qt, Kt, psum);
  k_rsum<<<dim3(64), 256, 0, stream>>>(psum, rcs);
  k_wprep<<<dim3(2048), 256, 0, stream>>>(w_co, wbf);
  for (int s = 0; s < stripes; ++s) {
    k_agen<<<dim3(stripeN / 64, 8), 512, 0, stream>>>(Qt, Kt, rcs, A, s * stripeN, stripeN);
    k_pv<<<dim3(stripeN / 16, 4), 256, 0, stream>>>(Vb, A, x, gamma, spatial, fusb, s * stripeN, stripeN);
  }
  k_deconv<<<dim3(16, 16), 512, 0, stream>>>(fusb, wbf, b_co, out);
}

// Round 8
// 482.516 us; speedup vs baseline: 1.0729x; 1.0084x over previous
//
#include <hip/hip_runtime.h>

#define BN 4
#define CC 256
#define NN 4096
#define CR 32
#define OCH 128
#define SEGS 8

typedef float f32x4 __attribute__((ext_vector_type(4)));
typedef short short8 __attribute__((ext_vector_type(8)));
typedef unsigned short u16x8 __attribute__((ext_vector_type(8)));
typedef unsigned short u16x4 __attribute__((ext_vector_type(4)));

__device__ __forceinline__ unsigned short f2b(float f) {
  unsigned u = __builtin_bit_cast(unsigned, f);
  u += 0x7fff + ((u >> 16) & 1);
  return (unsigned short)(u >> 16);
}
__device__ __forceinline__ float b2f(unsigned short h) {
  unsigned u = ((unsigned)h) << 16;
  return __builtin_bit_cast(float, u);
}

// ---------------------------------------------------------------------------
// cast wq / wv to bf16
__global__ __launch_bounds__(256) void k_wcast(const float* __restrict__ wq,
    const float* __restrict__ wv, unsigned short* __restrict__ wqb,
    unsigned short* __restrict__ wvb) {
  const int gid = (blockIdx.x * 256 + threadIdx.x) * 4;
  const float* src = blockIdx.y ? wv : wq;
  unsigned short* dst = blockIdx.y ? wvb : wqb;
  const float4 v = *(const float4*)(src + gid);
  u16x4 o; o[0] = f2b(v.x); o[1] = f2b(v.y); o[2] = f2b(v.z); o[3] = f2b(v.w);
  *(u16x4*)(dst + gid) = o;
}

// ---------------------------------------------------------------------------
// transpose+cast: x[b][c][n] f32 -> xt[b][n][c] bf16
__global__ __launch_bounds__(256) void k_xt(const float* __restrict__ x,
    unsigned short* __restrict__ xt) {
  __shared__ unsigned short T[64][65];
  const int b = blockIdx.z, c0 = blockIdx.y * 64, n0 = blockIdx.x * 64;
  const int t = threadIdx.x;
  for (int idx = t; idx < 4096; idx += 256) {
    int i = idx >> 6, j = idx & 63;
    T[i][j] = f2b(x[((size_t)(b * CC + c0 + i)) * NN + n0 + j]);
  }
  __syncthreads();
  for (int idx = t; idx < 4096; idx += 256) {
    int j = idx >> 6, i = idx & 63;
    xt[((size_t)(b * NN + n0 + j)) * CC + c0 + i] = T[i][j];
  }
}

// ---------------------------------------------------------------------------
// MFMA projection GEMM: out[b][c][n] = bias[c] + sum_j W[c][j] xt[b][n][j]
__global__ __launch_bounds__(256) void k_projm(const unsigned short* __restrict__ xt,
    const unsigned short* __restrict__ wqb, const float* __restrict__ bq,
    const unsigned short* __restrict__ wvb, const float* __restrict__ bv,
    unsigned short* __restrict__ q1b, unsigned short* __restrict__ Vb) {
  const int b = blockIdx.y, n0 = blockIdx.x * 32, which = blockIdx.z;
  const unsigned short* W = which ? wvb : wqb;
  const float* bias = which ? bv : bq;
  unsigned short* out = which ? Vb : q1b;
  const int t = threadIdx.x;
  const int w = t >> 6, l = t & 63;
  const int lo = l & 15, hi = l >> 4;
  const int oc0 = w * 64;
  f32x4 acc[4][2];
#pragma unroll
  for (int ct = 0; ct < 4; ++ct)
#pragma unroll
    for (int nt = 0; nt < 2; ++nt) acc[ct][nt] = (f32x4){0.f, 0.f, 0.f, 0.f};
  const unsigned short* wb = W + (size_t)(oc0 + lo) * CC + hi * 8;
  const unsigned short* xb = xt + ((size_t)(b * NN + n0 + lo)) * CC + hi * 8;
#pragma unroll
  for (int k0 = 0; k0 < CC; k0 += 32) {
    short8 aw[4], bx[2];
#pragma unroll
    for (int ct = 0; ct < 4; ++ct) aw[ct] = *(const short8*)(wb + ct * 16 * CC + k0);
#pragma unroll
    for (int nt = 0; nt < 2; ++nt) bx[nt] = *(const short8*)(xb + nt * 16 * CC + k0);
#pragma unroll
    for (int ct = 0; ct < 4; ++ct)
#pragma unroll
      for (int nt = 0; nt < 2; ++nt)
        acc[ct][nt] = __builtin_amdgcn_mfma_f32_16x16x32_bf16(aw[ct], bx[nt], acc[ct][nt], 0, 0, 0);
  }
#pragma unroll
  for (int ct = 0; ct < 4; ++ct) {
#pragma unroll
    for (int r = 0; r < 4; ++r) {
      const int c = oc0 + ct * 16 + hi * 4 + r;
      const float bvv = bias[c];
#pragma unroll
      for (int nt = 0; nt < 2; ++nt)
        out[((size_t)(b * CC + c)) * NN + n0 + nt * 16 + lo] = f2b(acc[ct][nt][r] + bvv);
    }
  }
}

// ---------------------------------------------------------------------------
// grouped conv1d (bf16 in, f32 out), vectorized: thread = 8 consecutive n
__global__ __launch_bounds__(256) void k_adj1(const unsigned short* __restrict__ q1,
    const float* __restrict__ w1, const float* __restrict__ b1,
    float* __restrict__ q2) {
  const int gid = blockIdx.x * 256 + threadIdx.x;   // B*32*(N/8) = 65536
  const int n8 = gid & 511;
  const int o = (gid >> 9) & 31;
  const int b = gid >> 14;
  const int n0 = n8 * 8;
  const unsigned short* base = q1 + ((size_t)b * CC + o * 8) * NN;
  float accv[8];
  const float bias = b1[o];
#pragma unroll
  for (int j = 0; j < 8; ++j) accv[j] = bias;
#pragma unroll
  for (int i = 0; i < 8; ++i) {
    const unsigned short* r = base + (size_t)i * NN;
    const u16x8 v = *(const u16x8*)(r + n0);
    float f[10];
    f[0] = (n0 > 0) ? b2f(r[n0 - 1]) : 0.f;
#pragma unroll
    for (int j = 0; j < 8; ++j) f[j + 1] = b2f(v[j]);
    f[9] = (n0 + 8 < NN) ? b2f(r[n0 + 8]) : 0.f;
    const float wa = w1[o * 24 + i * 3 + 0];
    const float wb = w1[o * 24 + i * 3 + 1];
    const float wc = w1[o * 24 + i * 3 + 2];
#pragma unroll
    for (int j = 0; j < 8; ++j) accv[j] += wa * f[j] + wb * f[j + 1] + wc * f[j + 2];
  }
  float4* dst = (float4*)&q2[((size_t)b * CR + o) * NN + n0];
  dst[0] = make_float4(accv[0], accv[1], accv[2], accv[3]);
  dst[1] = make_float4(accv[4], accv[5], accv[6], accv[7]);
}

// ---------------------------------------------------------------------------
// conv1d 32->64ch, writes bf16 TRANSPOSED Qt[b][n][32], Kt[b][n][32]
__global__ __launch_bounds__(256) void k_adj2(const float* __restrict__ q2,
    const float* __restrict__ w2, const float* __restrict__ b2,
    unsigned short* __restrict__ Qt, unsigned short* __restrict__ Kt) {
  __shared__ float q2s[32][66];
  __shared__ float w2t[96][64];
  __shared__ float b2s[64];
  const int b = blockIdx.y, n0 = blockIdx.x * 64;
  const int t = threadIdx.x;
  for (int idx = t; idx < 32 * 66; idx += 256) {
    int c = idx / 66, nn = idx % 66;
    int n = n0 + nn - 1;
    q2s[c][nn] = (n >= 0 && n < NN) ? q2[((size_t)b * CR + c) * NN + n] : 0.f;
  }
  for (int idx = t; idx < 96 * 64; idx += 256) {
    int k = idx & 63, ct = idx >> 6;
    w2t[ct][k] = w2[k * 96 + ct];
  }
  if (t < 64) b2s[t] = b2[t];
  __syncthreads();
  const int nn = t & 63, kh = t >> 6;
  float acc[16];
#pragma unroll
  for (int i = 0; i < 16; ++i) acc[i] = b2s[kh * 16 + i];
  for (int c = 0; c < 32; ++c) {
    const float x0 = q2s[c][nn], x1 = q2s[c][nn + 1], x2 = q2s[c][nn + 2];
    const float* wa = &w2t[c * 3 + 0][kh * 16];
    const float* wb = &w2t[c * 3 + 1][kh * 16];
    const float* wc = &w2t[c * 3 + 2][kh * 16];
#pragma unroll
    for (int i = 0; i < 16; ++i)
      acc[i] += wa[i] * x0 + wb[i] * x1 + wc[i] * x2;
  }
  const size_t row = ((size_t)b * NN + n0 + nn) * 32;
  u16x8 qo, ko;
#pragma unroll
  for (int i = 0; i < 8; ++i) {
    qo[i] = f2b(acc[2 * i]);
    ko[i] = f2b(acc[2 * i + 1]);
  }
  *(u16x8*)(Qt + row + kh * 8) = qo;
  *(u16x8*)(Kt + row + kh * 8) = ko;
}

// ---------------------------------------------------------------------------
// spatial mean of x per batch
__global__ __launch_bounds__(256) void k_spatial1(const float* __restrict__ x,
                                                  float* __restrict__ part) {
  const int b = blockIdx.y;
  const size_t off = (size_t)b * CC * NN + (size_t)blockIdx.x * 16384;
  float s = 0.f;
  for (int i = threadIdx.x; i < 16384; i += 256) s += x[off + i];
  __shared__ float red[256];
  red[threadIdx.x] = s;
  __syncthreads();
  for (int d = 128; d > 0; d >>= 1) {
    if (threadIdx.x < d) red[threadIdx.x] += red[threadIdx.x + d];
    __syncthreads();
  }
  if (threadIdx.x == 0) part[b * 64 + blockIdx.x] = red[0];
}

__global__ void k_spatial2(const float* __restrict__ part, float* __restrict__ spatial) {
  const int t = threadIdx.x;
  const int b = t >> 6, i = t & 63;
  float s = part[b * 64 + i];
  for (int d = 32; d > 0; d >>= 1) s += __shfl_down(s, d, 64);
  if (i == 0) spatial[b] = s * (1.0f / ((float)CC * NN));
}

// ---------------------------------------------------------------------------
// MFMA column exp-sum: psum[b][seg][m] = sum_{n in seg} exp(S[b][n][m])
__global__ __launch_bounds__(512) void k_colstatm(const unsigned short* __restrict__ Qt,
    const unsigned short* __restrict__ Kt, float* __restrict__ psum) {
  __shared__ float CS[2][4][64];
  const int m0 = blockIdx.x * 64, seg = blockIdx.y;
  const int t = threadIdx.x;
  const int w = t >> 6, l = t & 63;
  const int lo = l & 15, hi = l >> 4;
  const int mt = w & 3, nt2 = w >> 2;
  const f32x4 zero4 = (f32x4){0.f, 0.f, 0.f, 0.f};
  short8 kf[4];
#pragma unroll
  for (int bb = 0; bb < 4; ++bb)
    kf[bb] = *(const short8*)(Kt + ((size_t)(bb * NN + m0 + mt * 16 + lo)) * 32 + hi * 8);
  float colacc[4] = {0.f, 0.f, 0.f, 0.f};
  for (int ch = 0; ch < 8; ++ch) {
    const int nb = seg * 512 + ch * 64;
    short8 qf[2][4];
#pragma unroll
    for (int pos = 0; pos < 2; ++pos)
#pragma unroll
      for (int bb = 0; bb < 4; ++bb)
        qf[pos][bb] = *(const short8*)(Qt + ((size_t)(bb * NN + nb + (nt2 * 2 + pos) * 16 + lo)) * 32 + hi * 8);
#pragma unroll
    for (int pos = 0; pos < 2; ++pos) {
#pragma unroll
      for (int bb = 0; bb < 4; ++bb) {
        const f32x4 s = __builtin_amdgcn_mfma_f32_16x16x32_bf16(qf[pos][bb], kf[bb], zero4, 0, 0, 0);
#pragma unroll
        for (int r = 0; r < 4; ++r) colacc[bb] += __expf(fminf(s[r], 60.f));
      }
    }
  }
#pragma unroll
  for (int bb = 0; bb < 4; ++bb) {
    colacc[bb] += __shfl_xor(colacc[bb], 16, 64);
    colacc[bb] += __shfl_xor(colacc[bb], 32, 64);
  }
  if (hi == 0) {
#pragma unroll
    for (int bb = 0; bb < 4; ++bb) CS[nt2][bb][mt * 16 + lo] = colacc[bb];
  }
  __syncthreads();
  if (t < 256) {
    const int bb = t >> 6, mm = t & 63;
    psum[((size_t)(bb * SEGS + seg)) * NN + m0 + mm] = CS[0][bb][mm] + CS[1][bb][mm];
  }
}

__global__ void k_rsum(const float* __restrict__ psum, float* __restrict__ rcs) {
  const int gid = blockIdx.x * 256 + threadIdx.x;  // B*N = 16384
  const int b = gid >> 12, m = gid & (NN - 1);
  float S = 0.f;
#pragma unroll
  for (int s = 0; s < SEGS; ++s) S += psum[((size_t)(b * SEGS + s)) * NN + m];
  rcs[gid] = 1.0f / S;
}

// ---------------------------------------------------------------------------
// A-generation: S via MFMA (once per (n,m)), double softmax, write A bf16
// A layout: [4][stripeN][NN] m-contig.  grid (stripeN/64, 8 m-segs), 512 thr.
__global__ __launch_bounds__(512) void k_agen(const unsigned short* __restrict__ Qt,
    const unsigned short* __restrict__ Kt, const float* __restrict__ rcs,
    unsigned short* __restrict__ A, int n_base, int stripeN) {
  __shared__ unsigned short As[4][64][72];
  const int n0 = n_base + blockIdx.x * 64, mseg = blockIdx.y;
  const int t = threadIdx.x;
  const int w = t >> 6, l = t & 63;
  const int lo = l & 15, hi = l >> 4;
  const int mt = w & 3, nt2 = w >> 2;
  const f32x4 zero4 = (f32x4){0.f, 0.f, 0.f, 0.f};
  short8 qf[2][4];
#pragma unroll
  for (int pos = 0; pos < 2; ++pos)
#pragma unroll
    for (int bb = 0; bb < 4; ++bb)
      qf[pos][bb] = *(const short8*)(Qt + ((size_t)(bb * NN + n0 + (nt2 * 2 + pos) * 16 + lo)) * 32 + hi * 8);
  for (int ch = 0; ch < 8; ++ch) {
    const int m0 = mseg * 512 + ch * 64;
    const int mS = m0 + mt * 16 + lo;
    short8 kf[4];
#pragma unroll
    for (int bb = 0; bb < 4; ++bb)
      kf[bb] = *(const short8*)(Kt + ((size_t)(bb * NN + mS)) * 32 + hi * 8);
    f32x4 s[2][4];
#pragma unroll
    for (int pos = 0; pos < 2; ++pos)
#pragma unroll
      for (int bb = 0; bb < 4; ++bb)
        s[pos][bb] = __builtin_amdgcn_mfma_f32_16x16x32_bf16(qf[pos][bb], kf[bb], zero4, 0, 0, 0);
    float rc[4];
#pragma unroll
    for (int bb = 0; bb < 4; ++bb) rc[bb] = rcs[bb * NN + mS];
    unsigned short av[2][4][4];
#pragma unroll
    for (int pos = 0; pos < 2; ++pos) {
#pragma unroll
      for (int r = 0; r < 4; ++r) {
        float e[4];
#pragma unroll
        for (int bb = 0; bb < 4; ++bb) e[bb] = __expf(fminf(s[pos][bb][r], 60.f));
        const float rden = __builtin_amdgcn_rcpf(e[0] + e[1] + e[2] + e[3]);
#pragma unroll
        for (int bb = 0; bb < 4; ++bb) av[pos][r][bb] = f2b(e[bb] * (rden + rc[bb]));
      }
    }
    __syncthreads();   // previous copy-out done
#pragma unroll
    for (int pos = 0; pos < 2; ++pos) {
      const int nl0 = (nt2 * 2 + pos) * 16 + hi * 4;
      const int ml = mt * 16 + lo;
#pragma unroll
      for (int r = 0; r < 4; ++r)
#pragma unroll
        for (int bb = 0; bb < 4; ++bb) As[bb][nl0 + r][ml] = av[pos][r][bb];
    }
    __syncthreads();
    // coalesced copy-out: 2048 u16x8 units
#pragma unroll
    for (int q = 0; q < 4; ++q) {
      const int u = t + q * 512;
      const int bb = u >> 9, rest = u & 511;
      const int nl = rest >> 3, mg = (rest & 7) * 8;
      u16x8 v = *(const u16x8*)&As[bb][nl][mg];
      *(u16x8*)(A + ((size_t)bb * stripeN + (n0 - n_base) + nl) * NN + m0 + mg) = v;
    }
  }
}

// ---------------------------------------------------------------------------
// PV GEMM + epilogue v3: 32-n tiles, software-prefetched double-buffer.
// 1-D grid (4 * stripeN/32), 512 thr = 8 waves (cg = w&3: 64 c, nh = w>>2: 16 n).
// XCD swizzle: id&7 = 2b + parity pins each batch's V slice to 2 XCDs.
__global__ __launch_bounds__(512, 4) void k_pv(const unsigned short* __restrict__ Vb,
    const unsigned short* __restrict__ A, const float* __restrict__ x,
    const float* __restrict__ gamma, const float* __restrict__ spatial,
    unsigned short* __restrict__ fusb, int n_base, int stripeN) {
  __shared__ unsigned short Fs[32][264];
  const int id = blockIdx.x;
  const int b = (id & 7) >> 1;                      // XCD pair per batch
  const int bx = (((id >> 3) << 1) | (id & 1));     // n-tile index 0..nx-1
  const int nloc0 = bx * 32;
  const int t = threadIdx.x;
  const int w = t >> 6, l = t & 63;
  const int lo = l & 15, hi = l >> 4;
  const int cg = w & 3, nh = w >> 2;
  const f32x4 zero4 = (f32x4){0.f, 0.f, 0.f, 0.f};
  f32x4 acc[4];
#pragma unroll
  for (int ct = 0; ct < 4; ++ct) acc[ct] = zero4;
  const unsigned short* vb = Vb + ((size_t)(b * CC + cg * 64 + lo)) * NN + hi * 8;
  const unsigned short* ab = A + ((size_t)b * stripeN + nloc0 + nh * 16 + lo) * NN + hi * 8;

  // software-pipelined m-loop: chunk i+1's loads issue before chunk i's MFMAs
  short8 af = *(const short8*)(ab);
  short8 vf[4];
#pragma unroll
  for (int ct = 0; ct < 4; ++ct) vf[ct] = *(const short8*)(vb + (size_t)ct * 16 * NN);
#pragma unroll 2
  for (int m0 = 0; m0 < NN - 32; m0 += 32) {
    short8 afn = *(const short8*)(ab + m0 + 32);
    short8 vfn[4];
#pragma unroll
    for (int ct = 0; ct < 4; ++ct)
      vfn[ct] = *(const short8*)(vb + (size_t)ct * 16 * NN + m0 + 32);
#pragma unroll
    for (int ct = 0; ct < 4; ++ct)
      acc[ct] = __builtin_amdgcn_mfma_f32_16x16x32_bf16(vf[ct], af, acc[ct], 0, 0, 0);
    af = afn;
#pragma unroll
    for (int ct = 0; ct < 4; ++ct) vf[ct] = vfn[ct];
  }
#pragma unroll
  for (int ct = 0; ct < 4; ++ct)
    acc[ct] = __builtin_amdgcn_mfma_f32_16x16x32_bf16(vf[ct], af, acc[ct], 0, 0, 0);

  // epilogue: gamma*mean*acc + x -> bf16, staged via LDS for coalesced store
  const float g = gamma[0] * spatial[b];
  const int n_abs0 = n_base + nloc0;
  const int nl0 = nh * 16;
#pragma unroll
  for (int ct = 0; ct < 4; ++ct) {
    u16x4 o4;
#pragma unroll
    for (int r = 0; r < 4; ++r) {
      const int c = cg * 64 + ct * 16 + hi * 4 + r;
      const float xv = x[((size_t)(b * CC + c)) * NN + n_abs0 + nl0 + lo];
      o4[r] = f2b(g * acc[ct][r] + xv);
    }
    *(u16x4*)&Fs[nl0 + lo][cg * 64 + ct * 16 + hi * 4] = o4;
  }
  __syncthreads();
  const int iy = n_abs0 >> 6, ix0 = n_abs0 & 63;   // 32-aligned tile, same row
  unsigned short* fb = fusb + (((size_t)(b * 66 + iy + 1)) * 66 + ix0 + 1) * 256;
#pragma unroll
  for (int q = 0; q < 2; ++q) {
    const int u = t + q * 512;               // 0..1023
    const int nl = u >> 5, c0 = (u & 31) * 8;
    *(u16x8*)(fb + (size_t)nl * 256 + c0) = *(const u16x8*)&Fs[nl][c0];
  }
}

// ---------------------------------------------------------------------------
// weight transform: wbf[p][tap][o][ic] (bf16, ic contiguous)
__global__ void k_wprep(const float* __restrict__ w_co, unsigned short* __restrict__ wbf) {
  const int gid = blockIdx.x * 256 + threadIdx.x;
  const int ic = gid & 255;
  const int o = (gid >> 8) & 127;
  const int tap = (gid >> 15) & 3;
  const int p = gid >> 17;
  const int py = p >> 1, px = p & 1;
  const int tyi = tap >> 1, txi = tap & 1;
  const int ky = py + 2 * tyi, kx = px + 2 * txi;
  wbf[gid] = f2b(w_co[(ic * 128 + o) * 16 + (3 - ky) * 4 + (3 - kx)]);
}

// ---------------------------------------------------------------------------
// MFMA transposed conv
__global__ __launch_bounds__(512) void k_deconv(const unsigned short* __restrict__ fusb,
    const unsigned short* __restrict__ wbf, const float* __restrict__ b_co,
    float* __restrict__ out) {
  const int bp = blockIdx.y;
  const int b = bp >> 2, py = (bp >> 1) & 1, px = bp & 1;
  const int t = threadIdx.x;
  const int w = t >> 6, l = t & 63;
  const int lo = l & 15, hi = l >> 4;
  const int wm = w & 1, wrow = w >> 1;
  const int iy = blockIdx.x * 4 + wrow;
  f32x4 acc[4][4];
#pragma unroll
  for (int mt = 0; mt < 4; ++mt)
#pragma unroll
    for (int nt = 0; nt < 4; ++nt) acc[mt][nt] = (f32x4){0.f, 0.f, 0.f, 0.f};
  const unsigned short* wp_base = wbf + (size_t)(bp & 3) * 4 * 128 * 256;
  for (int tap = 0; tap < 4; ++tap) {
    const int tyi = tap >> 1, txi = tap & 1;
    const int dy = py + tyi - 1, dx = px + txi - 1;
    const unsigned short* wtap = wp_base + (size_t)tap * 128 * 256 + (size_t)(wm * 64 + lo) * 256 + hi * 8;
    const unsigned short* fb = fusb + ((size_t)(b * 66 + iy + dy + 1) * 66 + (lo + dx + 1)) * 256 + hi * 8;
#pragma unroll
    for (int ic0 = 0; ic0 < 256; ic0 += 32) {
      short8 a[4], bf[4];
#pragma unroll
      for (int mt = 0; mt < 4; ++mt) a[mt] = *(const short8*)(wtap + mt * 16 * 256 + ic0);
#pragma unroll
      for (int nt = 0; nt < 4; ++nt) bf[nt] = *(const short8*)(fb + nt * 16 * 256 + ic0);
#pragma unroll
      for (int mt = 0; mt < 4; ++mt)
#pragma unroll
        for (int nt = 0; nt < 4; ++nt)
          acc[mt][nt] = __builtin_amdgcn_mfma_f32_16x16x32_bf16(a[mt], bf[nt], acc[mt][nt], 0, 0, 0);
    }
  }
  const int y = 2 * iy + py;
#pragma unroll
  for (int mt = 0; mt < 4; ++mt) {
#pragma unroll
    for (int nt = 0; nt < 4; ++nt) {
#pragma unroll
      for (int r = 0; r < 4; ++r) {
        const int o = wm * 64 + mt * 16 + hi * 4 + r;
        const int xx = 2 * (nt * 16 + lo) + px;
        out[(((size_t)(b * OCH + o)) * 128 + y) * 128 + xx] = acc[mt][nt][r] + b_co[o];
      }
    }
  }
}

// ---------------------------------------------------------------------------
extern "C" void kernel_launch(void* const* d_in, const int* in_sizes, int n_in,
                              void* d_out, int out_size, void* d_ws, size_t ws_size,
                              hipStream_t stream) {
  const float* x     = (const float*)d_in[0];
  const float* wq    = (const float*)d_in[1];
  const float* bq    = (const float*)d_in[2];
  const float* wv    = (const float*)d_in[3];
  const float* bv    = (const float*)d_in[4];
  const float* w1    = (const float*)d_in[5];
  const float* b1    = (const float*)d_in[6];
  const float* w2    = (const float*)d_in[7];
  const float* b2    = (const float*)d_in[8];
  const float* gamma = (const float*)d_in[9];
  const float* w_co  = (const float*)d_in[10];
  const float* b_co  = (const float*)d_in[11];
  float* out = (float*)d_out;
  (void)in_sizes; (void)n_in; (void)out_size;

  // --- survivor region sizes (bytes) ---
  const size_t SZ_QT   = (size_t)BN * NN * 32 * 2;        // 1 MB
  const size_t SZ_VB   = (size_t)BN * CC * NN * 2;        // 8.4 MB
  const size_t SZ_RCS  = (size_t)BN * NN * 4;
  const size_t SZ_W    = (size_t)CC * CC * 2;             // 128 KB
  const size_t SZ_WBF  = (size_t)4 * 4 * 128 * 256 * 2;   // 1 MB
  const size_t SZ_FUSB = (size_t)BN * 66 * 66 * 256 * 2;  // 8.9 MB
  const size_t SURV = SZ_QT * 2 + SZ_VB + SZ_RCS + 256 + SZ_W * 2 + SZ_WBF + SZ_FUSB + 4096;

  // region0 holds early-dead temps, later overwritten by A
  const size_t SZ_XT  = (size_t)BN * NN * CC * 2;   // 8.4 MB
  const size_t SZ_Q1  = (size_t)BN * CC * NN * 2;   // 8.4 MB
  const size_t SZ_Q2  = (size_t)BN * CR * NN * 4;   // 2 MB
  const size_t SZ_PS  = (size_t)BN * SEGS * NN * 4; // 0.5 MB
  const size_t TEMPS  = SZ_XT + SZ_Q1 + SZ_Q2 + SZ_PS + 2048;

  int stripes;
  size_t a_bytes_full = (size_t)BN * NN * NN * 2;   // 134 MB
  if (ws_size >= a_bytes_full + SURV + (1 << 20)) stripes = 1;
  else if (ws_size >= a_bytes_full / 4 + SURV + (1 << 20) && a_bytes_full / 4 >= TEMPS) stripes = 4;
  else stripes = 8;
  const int stripeN = NN / stripes;
  const size_t R0 = (((size_t)BN * stripeN * NN * 2 > TEMPS) ? (size_t)BN * stripeN * NN * 2 : TEMPS);

  char* p0 = (char*)d_ws;
  unsigned short* A    = (unsigned short*)p0;
  unsigned short* xt   = (unsigned short*)p0;
  unsigned short* q1b  = (unsigned short*)(p0 + SZ_XT);
  float*          q2   = (float*)(p0 + SZ_XT + SZ_Q1);
  float*          psum = (float*)(p0 + SZ_XT + SZ_Q1 + SZ_Q2);
  float*          part = (float*)(p0 + SZ_XT + SZ_Q1 + SZ_Q2 + SZ_PS);

  char* ps = p0 + R0;
  unsigned short* Qt      = (unsigned short*)ps;            ps += SZ_QT;
  unsigned short* Kt      = (unsigned short*)ps;            ps += SZ_QT;
  unsigned short* Vb      = (unsigned short*)ps;            ps += SZ_VB;
  float*          rcs     = (float*)ps;                     ps += SZ_RCS;
  float*          spatial = (float*)ps;                     ps += 256;
  unsigned short* wqb     = (unsigned short*)ps;            ps += SZ_W;
  unsigned short* wvb     = (unsigned short*)ps;            ps += SZ_W;
  unsigned short* wbf     = (unsigned short*)ps;            ps += SZ_WBF;
  unsigned short* fusb    = (unsigned short*)ps;

  // border-zero padded fusion buffer
  hipMemsetAsync(fusb, 0, SZ_FUSB, stream);

  k_wcast<<<dim3(64, 2), 256, 0, stream>>>(wq, wv, wqb, wvb);
  k_xt<<<dim3(64, 4, 4), 256, 0, stream>>>(x, xt);
  k_projm<<<dim3(128, 4, 2), 256, 0, stream>>>(xt, wqb, bq, wvb, bv, q1b, Vb);
  k_adj1<<<dim3(256), 256, 0, stream>>>(q1b, w1, b1, q2);
  k_adj2<<<dim3(64, 4), 256, 0, stream>>>(q2, w2, b2, Qt, Kt);
  k_spatial1<<<dim3(64, 4), 256, 0, stream>>>(x, part);
  k_spatial2<<<dim3(1), 256, 0, stream>>>(part, spatial);
  k_colstatm<<<dim3(64, SEGS), 512, 0, stream>>>(Qt, Kt, psum);
  k_rsum<<<dim3(64), 256, 0, stream>>>(psum, rcs);
  k_wprep<<<dim3(2048), 256, 0, stream>>>(w_co, wbf);
  for (int s = 0; s < stripes; ++s) {
    k_agen<<<dim3(stripeN / 64, 8), 512, 0, stream>>>(Qt, Kt, rcs, A, s * stripeN, stripeN);
    k_pv<<<dim3(4 * (stripeN / 32)), 512, 0, stream>>>(Vb, A, x, gamma, spatial, fusb, s * stripeN, stripeN);
  }
  k_deconv<<<dim3(16, 16), 512, 0, stream>>>(fusb, wbf, b_co, out);
}

// Round 9
// 287.780 us; speedup vs baseline: 1.7989x; 1.6767x over previous
//
#include <hip/hip_runtime.h>

#define BN 4
#define CC 256
#define NN 4096
#define CR 32
#define OCH 128
#define SEGS 8

typedef float f32x4 __attribute__((ext_vector_type(4)));
typedef short short8 __attribute__((ext_vector_type(8)));
typedef unsigned short u16x8 __attribute__((ext_vector_type(8)));
typedef unsigned short u16x4 __attribute__((ext_vector_type(4)));

__device__ __forceinline__ unsigned short f2b(float f) {
  unsigned u = __builtin_bit_cast(unsigned, f);
  u += 0x7fff + ((u >> 16) & 1);
  return (unsigned short)(u >> 16);
}
__device__ __forceinline__ float b2f(unsigned short h) {
  unsigned u = ((unsigned)h) << 16;
  return __builtin_bit_cast(float, u);
}

// ---------------------------------------------------------------------------
// cast wq / wv to bf16
__global__ __launch_bounds__(256) void k_wcast(const float* __restrict__ wq,
    const float* __restrict__ wv, unsigned short* __restrict__ wqb,
    unsigned short* __restrict__ wvb) {
  const int gid = (blockIdx.x * 256 + threadIdx.x) * 4;
  const float* src = blockIdx.y ? wv : wq;
  unsigned short* dst = blockIdx.y ? wvb : wqb;
  const float4 v = *(const float4*)(src + gid);
  u16x4 o; o[0] = f2b(v.x); o[1] = f2b(v.y); o[2] = f2b(v.z); o[3] = f2b(v.w);
  *(u16x4*)(dst + gid) = o;
}

// ---------------------------------------------------------------------------
// transpose+cast: x[b][c][n] f32 -> xt[b][n][c] bf16
__global__ __launch_bounds__(256) void k_xt(const float* __restrict__ x,
    unsigned short* __restrict__ xt) {
  __shared__ unsigned short T[64][65];
  const int b = blockIdx.z, c0 = blockIdx.y * 64, n0 = blockIdx.x * 64;
  const int t = threadIdx.x;
  for (int idx = t; idx < 4096; idx += 256) {
    int i = idx >> 6, j = idx & 63;
    T[i][j] = f2b(x[((size_t)(b * CC + c0 + i)) * NN + n0 + j]);
  }
  __syncthreads();
  for (int idx = t; idx < 4096; idx += 256) {
    int j = idx >> 6, i = idx & 63;
    xt[((size_t)(b * NN + n0 + j)) * CC + c0 + i] = T[i][j];
  }
}

// ---------------------------------------------------------------------------
// MFMA projection GEMM: out[b][c][n] = bias[c] + sum_j W[c][j] xt[b][n][j]
__global__ __launch_bounds__(256) void k_projm(const unsigned short* __restrict__ xt,
    const unsigned short* __restrict__ wqb, const float* __restrict__ bq,
    const unsigned short* __restrict__ wvb, const float* __restrict__ bv,
    unsigned short* __restrict__ q1b, unsigned short* __restrict__ Vb) {
  const int b = blockIdx.y, n0 = blockIdx.x * 32, which = blockIdx.z;
  const unsigned short* W = which ? wvb : wqb;
  const float* bias = which ? bv : bq;
  unsigned short* out = which ? Vb : q1b;
  const int t = threadIdx.x;
  const int w = t >> 6, l = t & 63;
  const int lo = l & 15, hi = l >> 4;
  const int oc0 = w * 64;
  f32x4 acc[4][2];
#pragma unroll
  for (int ct = 0; ct < 4; ++ct)
#pragma unroll
    for (int nt = 0; nt < 2; ++nt) acc[ct][nt] = (f32x4){0.f, 0.f, 0.f, 0.f};
  const unsigned short* wb = W + (size_t)(oc0 + lo) * CC + hi * 8;
  const unsigned short* xb = xt + ((size_t)(b * NN + n0 + lo)) * CC + hi * 8;
#pragma unroll
  for (int k0 = 0; k0 < CC; k0 += 32) {
    short8 aw[4], bx[2];
#pragma unroll
    for (int ct = 0; ct < 4; ++ct) aw[ct] = *(const short8*)(wb + ct * 16 * CC + k0);
#pragma unroll
    for (int nt = 0; nt < 2; ++nt) bx[nt] = *(const short8*)(xb + nt * 16 * CC + k0);
#pragma unroll
    for (int ct = 0; ct < 4; ++ct)
#pragma unroll
      for (int nt = 0; nt < 2; ++nt)
        acc[ct][nt] = __builtin_amdgcn_mfma_f32_16x16x32_bf16(aw[ct], bx[nt], acc[ct][nt], 0, 0, 0);
  }
#pragma unroll
  for (int ct = 0; ct < 4; ++ct) {
#pragma unroll
    for (int r = 0; r < 4; ++r) {
      const int c = oc0 + ct * 16 + hi * 4 + r;
      const float bvv = bias[c];
#pragma unroll
      for (int nt = 0; nt < 2; ++nt)
        out[((size_t)(b * CC + c)) * NN + n0 + nt * 16 + lo] = f2b(acc[ct][nt][r] + bvv);
    }
  }
}

// ---------------------------------------------------------------------------
// grouped conv1d (bf16 in, f32 out), vectorized: thread = 8 consecutive n
__global__ __launch_bounds__(256) void k_adj1(const unsigned short* __restrict__ q1,
    const float* __restrict__ w1, const float* __restrict__ b1,
    float* __restrict__ q2) {
  const int gid = blockIdx.x * 256 + threadIdx.x;   // B*32*(N/8) = 65536
  const int n8 = gid & 511;
  const int o = (gid >> 9) & 31;
  const int b = gid >> 14;
  const int n0 = n8 * 8;
  const unsigned short* base = q1 + ((size_t)b * CC + o * 8) * NN;
  float accv[8];
  const float bias = b1[o];
#pragma unroll
  for (int j = 0; j < 8; ++j) accv[j] = bias;
#pragma unroll
  for (int i = 0; i < 8; ++i) {
    const unsigned short* r = base + (size_t)i * NN;
    const u16x8 v = *(const u16x8*)(r + n0);
    float f[10];
    f[0] = (n0 > 0) ? b2f(r[n0 - 1]) : 0.f;
#pragma unroll
    for (int j = 0; j < 8; ++j) f[j + 1] = b2f(v[j]);
    f[9] = (n0 + 8 < NN) ? b2f(r[n0 + 8]) : 0.f;
    const float wa = w1[o * 24 + i * 3 + 0];
    const float wb = w1[o * 24 + i * 3 + 1];
    const float wc = w1[o * 24 + i * 3 + 2];
#pragma unroll
    for (int j = 0; j < 8; ++j) accv[j] += wa * f[j] + wb * f[j + 1] + wc * f[j + 2];
  }
  float4* dst = (float4*)&q2[((size_t)b * CR + o) * NN + n0];
  dst[0] = make_float4(accv[0], accv[1], accv[2], accv[3]);
  dst[1] = make_float4(accv[4], accv[5], accv[6], accv[7]);
}

// ---------------------------------------------------------------------------
// conv1d 32->64ch, writes bf16 TRANSPOSED Qt[b][n][32], Kt[b][n][32]
__global__ __launch_bounds__(256) void k_adj2(const float* __restrict__ q2,
    const float* __restrict__ w2, const float* __restrict__ b2,
    unsigned short* __restrict__ Qt, unsigned short* __restrict__ Kt) {
  __shared__ float q2s[32][66];
  __shared__ float w2t[96][64];
  __shared__ float b2s[64];
  const int b = blockIdx.y, n0 = blockIdx.x * 64;
  const int t = threadIdx.x;
  for (int idx = t; idx < 32 * 66; idx += 256) {
    int c = idx / 66, nn = idx % 66;
    int n = n0 + nn - 1;
    q2s[c][nn] = (n >= 0 && n < NN) ? q2[((size_t)b * CR + c) * NN + n] : 0.f;
  }
  for (int idx = t; idx < 96 * 64; idx += 256) {
    int k = idx & 63, ct = idx >> 6;
    w2t[ct][k] = w2[k * 96 + ct];
  }
  if (t < 64) b2s[t] = b2[t];
  __syncthreads();
  const int nn = t & 63, kh = t >> 6;
  float acc[16];
#pragma unroll
  for (int i = 0; i < 16; ++i) acc[i] = b2s[kh * 16 + i];
  for (int c = 0; c < 32; ++c) {
    const float x0 = q2s[c][nn], x1 = q2s[c][nn + 1], x2 = q2s[c][nn + 2];
    const float* wa = &w2t[c * 3 + 0][kh * 16];
    const float* wb = &w2t[c * 3 + 1][kh * 16];
    const float* wc = &w2t[c * 3 + 2][kh * 16];
#pragma unroll
    for (int i = 0; i < 16; ++i)
      acc[i] += wa[i] * x0 + wb[i] * x1 + wc[i] * x2;
  }
  const size_t row = ((size_t)b * NN + n0 + nn) * 32;
  u16x8 qo, ko;
#pragma unroll
  for (int i = 0; i < 8; ++i) {
    qo[i] = f2b(acc[2 * i]);
    ko[i] = f2b(acc[2 * i + 1]);
  }
  *(u16x8*)(Qt + row + kh * 8) = qo;
  *(u16x8*)(Kt + row + kh * 8) = ko;
}

// ---------------------------------------------------------------------------
// spatial mean of x per batch
__global__ __launch_bounds__(256) void k_spatial1(const float* __restrict__ x,
                                                  float* __restrict__ part) {
  const int b = blockIdx.y;
  const size_t off = (size_t)b * CC * NN + (size_t)blockIdx.x * 16384;
  float s = 0.f;
  for (int i = threadIdx.x; i < 16384; i += 256) s += x[off + i];
  __shared__ float red[256];
  red[threadIdx.x] = s;
  __syncthreads();
  for (int d = 128; d > 0; d >>= 1) {
    if (threadIdx.x < d) red[threadIdx.x] += red[threadIdx.x + d];
    __syncthreads();
  }
  if (threadIdx.x == 0) part[b * 64 + blockIdx.x] = red[0];
}

__global__ void k_spatial2(const float* __restrict__ part, float* __restrict__ spatial) {
  const int t = threadIdx.x;
  const int b = t >> 6, i = t & 63;
  float s = part[b * 64 + i];
  for (int d = 32; d > 0; d >>= 1) s += __shfl_down(s, d, 64);
  if (i == 0) spatial[b] = s * (1.0f / ((float)CC * NN));
}

// ---------------------------------------------------------------------------
// MFMA column exp-sum: psum[b][seg][m] = sum_{n in seg} exp(S[b][n][m])
__global__ __launch_bounds__(512) void k_colstatm(const unsigned short* __restrict__ Qt,
    const unsigned short* __restrict__ Kt, float* __restrict__ psum) {
  __shared__ float CS[2][4][64];
  const int m0 = blockIdx.x * 64, seg = blockIdx.y;
  const int t = threadIdx.x;
  const int w = t >> 6, l = t & 63;
  const int lo = l & 15, hi = l >> 4;
  const int mt = w & 3, nt2 = w >> 2;
  const f32x4 zero4 = (f32x4){0.f, 0.f, 0.f, 0.f};
  short8 kf[4];
#pragma unroll
  for (int bb = 0; bb < 4; ++bb)
    kf[bb] = *(const short8*)(Kt + ((size_t)(bb * NN + m0 + mt * 16 + lo)) * 32 + hi * 8);
  float colacc[4] = {0.f, 0.f, 0.f, 0.f};
  for (int ch = 0; ch < 8; ++ch) {
    const int nb = seg * 512 + ch * 64;
    short8 qf[2][4];
#pragma unroll
    for (int pos = 0; pos < 2; ++pos)
#pragma unroll
      for (int bb = 0; bb < 4; ++bb)
        qf[pos][bb] = *(const short8*)(Qt + ((size_t)(bb * NN + nb + (nt2 * 2 + pos) * 16 + lo)) * 32 + hi * 8);
#pragma unroll
    for (int pos = 0; pos < 2; ++pos) {
#pragma unroll
      for (int bb = 0; bb < 4; ++bb) {
        const f32x4 s = __builtin_amdgcn_mfma_f32_16x16x32_bf16(qf[pos][bb], kf[bb], zero4, 0, 0, 0);
#pragma unroll
        for (int r = 0; r < 4; ++r) colacc[bb] += __expf(fminf(s[r], 60.f));
      }
    }
  }
#pragma unroll
  for (int bb = 0; bb < 4; ++bb) {
    colacc[bb] += __shfl_xor(colacc[bb], 16, 64);
    colacc[bb] += __shfl_xor(colacc[bb], 32, 64);
  }
  if (hi == 0) {
#pragma unroll
    for (int bb = 0; bb < 4; ++bb) CS[nt2][bb][mt * 16 + lo] = colacc[bb];
  }
  __syncthreads();
  if (t < 256) {
    const int bb = t >> 6, mm = t & 63;
    psum[((size_t)(bb * SEGS + seg)) * NN + m0 + mm] = CS[0][bb][mm] + CS[1][bb][mm];
  }
}

__global__ void k_rsum(const float* __restrict__ psum, float* __restrict__ rcs) {
  const int gid = blockIdx.x * 256 + threadIdx.x;  // B*N = 16384
  const int b = gid >> 12, m = gid & (NN - 1);
  float S = 0.f;
#pragma unroll
  for (int s = 0; s < SEGS; ++s) S += psum[((size_t)(b * SEGS + s)) * NN + m];
  rcs[gid] = 1.0f / S;
}

// ---------------------------------------------------------------------------
// Fused attention v8: LDS-staged, coalesced. Block (b, 32n), 512 thr = 8 waves.
// Per 64-m chunk:
//   issue V-tile loads (coalesced, write-late, swizzled LDS) + next K-tile loads
//   S phase: K-frags from padded LDS (double-buffered), 4 MFMA/wave,
//   in-register double softmax -> swizzled A-tile LDS
//   barrier; PV entirely from LDS (b128 reads, <=2-way conflicts); barrier.
// Epilogue: gamma*mean*acc + x -> channels-last bf16 fusb (LDS-staged store).
__global__ __launch_bounds__(512, 4) void k_fused2(const unsigned short* __restrict__ Qt,
    const unsigned short* __restrict__ Kt, const unsigned short* __restrict__ Vb,
    const float* __restrict__ x, const float* __restrict__ rcs,
    const float* __restrict__ gamma, const float* __restrict__ spatial,
    unsigned short* __restrict__ fusb) {
  __shared__ unsigned short Vs[256 * 64];        // 32 KB, swizzled [c][m]
  __shared__ unsigned short Ks[2][4 * 64 * 40];  // 41 KB, padded rows, dbuf
  __shared__ unsigned short As[32 * 80];         // 5 KB, swizzled [n][m]
  const int id = blockIdx.x;
  const int b = (id & 7) >> 1;                   // batch pinned to XCD pair
  const int ntile = ((id >> 3) << 1) | (id & 1); // 0..127
  const int n0 = ntile * 32;
  const int t = threadIdx.x;
  const int w = t >> 6, l = t & 63;
  const int lo = l & 15, hi = l >> 4;
  const int mt = w & 3, nt2 = w >> 2;            // S role: 16m x 16n tile
  const int cg = w & 3, nh = w >> 2;             // PV role: 64c x 16n
  const f32x4 zero4 = (f32x4){0.f, 0.f, 0.f, 0.f};

  short8 qf[4];
#pragma unroll
  for (int bb = 0; bb < 4; ++bb)
    qf[bb] = *(const short8*)(Qt + ((size_t)(bb * NN + n0 + nt2 * 16 + lo)) * 32 + hi * 8);

  f32x4 acc[4];
#pragma unroll
  for (int ct = 0; ct < 4; ++ct) acc[ct] = zero4;

  const unsigned short* vbase = Vb + (size_t)b * CC * NN;
  const float* rcs_b = rcs + b * NN;

  // prologue: stage K chunk 0 into Ks[0] (coalesced loads -> padded rows)
#pragma unroll
  for (int q = 0; q < 2; ++q) {
    const int idx = t * 2 + q;
    const int bb = idx >> 8, m = (idx >> 2) & 63, hf = idx & 3;
    u16x8 v = *(const u16x8*)(Kt + ((size_t)(bb * NN + m)) * 32 + hf * 8);
    *(u16x8*)&Ks[0][(bb * 64 + m) * 40 + hf * 8] = v;
  }
  __syncthreads();

  for (int ch = 0; ch < 64; ++ch) {
    const int cur = ch & 1;
    const int m0 = ch * 64;
    // ---- issue V loads for THIS chunk (coalesced; written to LDS later)
    u16x8 vst[4];
#pragma unroll
    for (int q = 0; q < 4; ++q) {
      const int c16 = q * 512 + t;
      const int c = c16 >> 3, j = c16 & 7;
      vst[q] = *(const u16x8*)(vbase + (size_t)c * NN + m0 + j * 8);
    }
    // ---- issue K loads for NEXT chunk
    u16x8 kst[2];
    const int mnext = (ch < 63) ? (m0 + 64) : m0;
#pragma unroll
    for (int q = 0; q < 2; ++q) {
      const int idx = t * 2 + q;
      const int bb = idx >> 8, m = (idx >> 2) & 63, hf = idx & 3;
      kst[q] = *(const u16x8*)(Kt + ((size_t)(bb * NN + mnext + m)) * 32 + hf * 8);
    }
    const float rc = rcs_b[m0 + mt * 16 + lo];
    // ---- S phase (Ks[cur] staged last iteration)
    short8 kf[4];
#pragma unroll
    for (int bb = 0; bb < 4; ++bb)
      kf[bb] = *(const short8*)&Ks[cur][(bb * 64 + mt * 16 + lo) * 40 + hi * 8];
    f32x4 s[4];
#pragma unroll
    for (int bb = 0; bb < 4; ++bb)
      s[bb] = __builtin_amdgcn_mfma_f32_16x16x32_bf16(qf[bb], kf[bb], zero4, 0, 0, 0);
#pragma unroll
    for (int r = 0; r < 4; ++r) {
      const float e0 = __expf(fminf(s[0][r], 60.f));
      const float e1 = __expf(fminf(s[1][r], 60.f));
      const float e2 = __expf(fminf(s[2][r], 60.f));
      const float e3 = __expf(fminf(s[3][r], 60.f));
      const float eb = b == 0 ? e0 : (b == 1 ? e1 : (b == 2 ? e2 : e3));
      const float a = eb * (__builtin_amdgcn_rcpf(e0 + e1 + e2 + e3) + rc);
      const int nl = nt2 * 16 + hi * 4 + r;
      const int ml = mt * 16 + lo;
      As[nl * 80 + (ml ^ ((nl & 7) << 3))] = f2b(a);
    }
    // ---- write-late staged tiles (V swizzled; K next buffer)
#pragma unroll
    for (int q = 0; q < 4; ++q) {
      const int c16 = q * 512 + t;
      const int c = c16 >> 3, j = c16 & 7;
      *(u16x8*)&Vs[c * 64 + ((j ^ (c & 7)) << 3)] = vst[q];
    }
    if (ch < 63) {
#pragma unroll
      for (int q = 0; q < 2; ++q) {
        const int idx = t * 2 + q;
        const int bb = idx >> 8, m = (idx >> 2) & 63, hf = idx & 3;
        *(u16x8*)&Ks[cur ^ 1][(bb * 64 + m) * 40 + hf * 8] = kst[q];
      }
    }
    __syncthreads();   // As + Vs ready
    // ---- PV from LDS: acc[ct] covers c = cg*64+ct*16+hi*4+r, n = n0+nh*16+lo
#pragma unroll
    for (int kt = 0; kt < 2; ++kt) {
      const int nl = nh * 16 + lo;
      const short8 af = *(const short8*)&As[nl * 80 + ((kt * 32 + hi * 8) ^ ((nl & 7) << 3))];
#pragma unroll
      for (int ct = 0; ct < 4; ++ct) {
        const int c = cg * 64 + ct * 16 + lo;
        const short8 vf = *(const short8*)&Vs[c * 64 + (((kt * 4 + hi) ^ (c & 7)) << 3)];
        acc[ct] = __builtin_amdgcn_mfma_f32_16x16x32_bf16(vf, af, acc[ct], 0, 0, 0);
      }
    }
    __syncthreads();   // PV done before next chunk restages Vs/As
  }

  // ---- epilogue: gamma*mean*acc + x -> Fs (reuse Ks LDS) -> coalesced fusb
  unsigned short* Fs = &Ks[0][0];
  const float g = gamma[0] * spatial[b];
#pragma unroll
  for (int ct = 0; ct < 4; ++ct) {
    u16x4 o4;
#pragma unroll
    for (int r = 0; r < 4; ++r) {
      const int c = cg * 64 + ct * 16 + hi * 4 + r;
      const float xv = x[((size_t)(b * CC + c)) * NN + n0 + nh * 16 + lo];
      o4[r] = f2b(g * acc[ct][r] + xv);
    }
    *(u16x4*)&Fs[(nh * 16 + lo) * 264 + cg * 64 + ct * 16 + hi * 4] = o4;
  }
  __syncthreads();
  const int iy = n0 >> 6, ix0 = n0 & 63;
  unsigned short* fb = fusb + (((size_t)(b * 66 + iy + 1)) * 66 + ix0 + 1) * 256;
#pragma unroll
  for (int q = 0; q < 2; ++q) {
    const int u = t + q * 512;               // 0..1023
    const int nl = u >> 5, c0 = (u & 31) * 8;
    *(u16x8*)(fb + (size_t)nl * 256 + c0) = *(const u16x8*)&Fs[nl * 264 + c0];
  }
}

// ---------------------------------------------------------------------------
// weight transform: wbf[p][tap][o][ic] (bf16, ic contiguous)
__global__ void k_wprep(const float* __restrict__ w_co, unsigned short* __restrict__ wbf) {
  const int gid = blockIdx.x * 256 + threadIdx.x;
  const int ic = gid & 255;
  const int o = (gid >> 8) & 127;
  const int tap = (gid >> 15) & 3;
  const int p = gid >> 17;
  const int py = p >> 1, px = p & 1;
  const int tyi = tap >> 1, txi = tap & 1;
  const int ky = py + 2 * tyi, kx = px + 2 * txi;
  wbf[gid] = f2b(w_co[(ic * 128 + o) * 16 + (3 - ky) * 4 + (3 - kx)]);
}

// ---------------------------------------------------------------------------
// MFMA transposed conv
__global__ __launch_bounds__(512) void k_deconv(const unsigned short* __restrict__ fusb,
    const unsigned short* __restrict__ wbf, const float* __restrict__ b_co,
    float* __restrict__ out) {
  const int bp = blockIdx.y;
  const int b = bp >> 2, py = (bp >> 1) & 1, px = bp & 1;
  const int t = threadIdx.x;
  const int w = t >> 6, l = t & 63;
  const int lo = l & 15, hi = l >> 4;
  const int wm = w & 1, wrow = w >> 1;
  const int iy = blockIdx.x * 4 + wrow;
  f32x4 acc[4][4];
#pragma unroll
  for (int mt = 0; mt < 4; ++mt)
#pragma unroll
    for (int nt = 0; nt < 4; ++nt) acc[mt][nt] = (f32x4){0.f, 0.f, 0.f, 0.f};
  const unsigned short* wp_base = wbf + (size_t)(bp & 3) * 4 * 128 * 256;
  for (int tap = 0; tap < 4; ++tap) {
    const int tyi = tap >> 1, txi = tap & 1;
    const int dy = py + tyi - 1, dx = px + txi - 1;
    const unsigned short* wtap = wp_base + (size_t)tap * 128 * 256 + (size_t)(wm * 64 + lo) * 256 + hi * 8;
    const unsigned short* fb = fusb + ((size_t)(b * 66 + iy + dy + 1) * 66 + (lo + dx + 1)) * 256 + hi * 8;
#pragma unroll
    for (int ic0 = 0; ic0 < 256; ic0 += 32) {
      short8 a[4], bf[4];
#pragma unroll
      for (int mt = 0; mt < 4; ++mt) a[mt] = *(const short8*)(wtap + mt * 16 * 256 + ic0);
#pragma unroll
      for (int nt = 0; nt < 4; ++nt) bf[nt] = *(const short8*)(fb + nt * 16 * 256 + ic0);
#pragma unroll
      for (int mt = 0; mt < 4; ++mt)
#pragma unroll
        for (int nt = 0; nt < 4; ++nt)
          acc[mt][nt] = __builtin_amdgcn_mfma_f32_16x16x32_bf16(a[mt], bf[nt], acc[mt][nt], 0, 0, 0);
    }
  }
  const int y = 2 * iy + py;
#pragma unroll
  for (int mt = 0; mt < 4; ++mt) {
#pragma unroll
    for (int nt = 0; nt < 4; ++nt) {
#pragma unroll
      for (int r = 0; r < 4; ++r) {
        const int o = wm * 64 + mt * 16 + hi * 4 + r;
        const int xx = 2 * (nt * 16 + lo) + px;
        out[(((size_t)(b * OCH + o)) * 128 + y) * 128 + xx] = acc[mt][nt][r] + b_co[o];
      }
    }
  }
}

// ---------------------------------------------------------------------------
extern "C" void kernel_launch(void* const* d_in, const int* in_sizes, int n_in,
                              void* d_out, int out_size, void* d_ws, size_t ws_size,
                              hipStream_t stream) {
  const float* x     = (const float*)d_in[0];
  const float* wq    = (const float*)d_in[1];
  const float* bq    = (const float*)d_in[2];
  const float* wv    = (const float*)d_in[3];
  const float* bv    = (const float*)d_in[4];
  const float* w1    = (const float*)d_in[5];
  const float* b1    = (const float*)d_in[6];
  const float* w2    = (const float*)d_in[7];
  const float* b2    = (const float*)d_in[8];
  const float* gamma = (const float*)d_in[9];
  const float* w_co  = (const float*)d_in[10];
  const float* b_co  = (const float*)d_in[11];
  float* out = (float*)d_out;
  (void)in_sizes; (void)n_in; (void)out_size; (void)ws_size;

  char* p = (char*)d_ws;
  unsigned short* xt      = (unsigned short*)p; p += (size_t)BN * NN * CC * 2;      // 8.4 MB
  unsigned short* q1b     = (unsigned short*)p; p += (size_t)BN * CC * NN * 2;      // 8.4 MB
  float*          q2      = (float*)p;          p += (size_t)BN * CR * NN * 4;      // 2 MB
  float*          psum    = (float*)p;          p += (size_t)BN * SEGS * NN * 4;    // 0.5 MB
  float*          part    = (float*)p;          p += (size_t)256 * 4;
  unsigned short* Qt      = (unsigned short*)p; p += (size_t)BN * NN * 32 * 2;      // 1 MB
  unsigned short* Kt      = (unsigned short*)p; p += (size_t)BN * NN * 32 * 2;      // 1 MB
  unsigned short* Vb      = (unsigned short*)p; p += (size_t)BN * CC * NN * 2;      // 8.4 MB
  float*          rcs     = (float*)p;          p += (size_t)BN * NN * 4;
  float*          spatial = (float*)p;          p += 256;
  unsigned short* wqb     = (unsigned short*)p; p += (size_t)CC * CC * 2;
  unsigned short* wvb     = (unsigned short*)p; p += (size_t)CC * CC * 2;
  unsigned short* wbf     = (unsigned short*)p; p += (size_t)4 * 4 * 128 * 256 * 2; // 1 MB
  unsigned short* fusb    = (unsigned short*)p;                                     // 8.9 MB

  // border-zero padded fusion buffer
  hipMemsetAsync(fusb, 0, (size_t)BN * 66 * 66 * 256 * 2, stream);

  k_wcast<<<dim3(64, 2), 256, 0, stream>>>(wq, wv, wqb, wvb);
  k_xt<<<dim3(64, 4, 4), 256, 0, stream>>>(x, xt);
  k_projm<<<dim3(128, 4, 2), 256, 0, stream>>>(xt, wqb, bq, wvb, bv, q1b, Vb);
  k_adj1<<<dim3(256), 256, 0, stream>>>(q1b, w1, b1, q2);
  k_adj2<<<dim3(64, 4), 256, 0, stream>>>(q2, w2, b2, Qt, Kt);
  k_spatial1<<<dim3(64, 4), 256, 0, stream>>>(x, part);
  k_spatial2<<<dim3(1), 256, 0, stream>>>(part, spatial);
  k_colstatm<<<dim3(64, SEGS), 512, 0, stream>>>(Qt, Kt, psum);
  k_rsum<<<dim3(64), 256, 0, stream>>>(psum, rcs);
  k_wprep<<<dim3(2048), 256, 0, stream>>>(w_co, wbf);
  k_fused2<<<dim3(512), 512, 0, stream>>>(Qt, Kt, Vb, x, rcs, gamma, spatial, fusb);
  k_deconv<<<dim3(16, 16), 512, 0, stream>>>(fusb, wbf, b_co, out);
}